// Round 11
// baseline (795.643 us; speedup 1.0000x reference)
//
#include <hip/hip_runtime.h>
#include <hip/hip_fp16.h>
#include <math.h>

#define L 64
#define FIXS 1048576.0f   // 2^20 fixed-point scale for attr histogram
#define WAITCNT_LGKM0 0xC07F   // vmcnt=63, expcnt=7, lgkmcnt=0

// packed-half helpers with pinned types (avoids bf16-header overload ambiguity)
static __device__ __forceinline__ __half2 h2add(__half2 a, __half2 b) {
    return __half2{__hadd(a.x, b.x), __hadd(a.y, b.y)};
}
static __device__ __forceinline__ __half2 h2relu(__half2 a) {
    const __half z = __float2half(0.f);
    return __half2{__hgt(a.x, z) ? a.x : z, __hgt(a.y, z) ? a.y : z};
}

// ---------- preprocessing ----------

__global__ void k_hist(const int* __restrict__ col, const float* __restrict__ attr,
                       unsigned long long* __restrict__ degcnt, int E) {
    int e = blockIdx.x * blockDim.x + threadIdx.x;
    if (e < E) {
        int c = col[e];
        unsigned int fx = (unsigned int)(int)rintf(attr[e] * FIXS);
        atomicAdd(&degcnt[c], (1ULL << 32) | (unsigned long long)fx);
    }
}

__global__ void k_dinv(const unsigned long long* __restrict__ degcnt,
                       float* __restrict__ dinv, int* __restrict__ cntI,
                       float* __restrict__ rcnt, int N) {
    int n = blockIdx.x * blockDim.x + threadIdx.x;
    if (n < N) {
        unsigned long long p = degcnt[n];
        int cnt = (int)(p >> 32);
        float d = (float)(unsigned int)(p & 0xffffffffULL) * (1.0f / FIXS);
        dinv[n] = (d > 0.f) ? (1.0f / sqrtf(fmaxf(d, 1e-30f))) : 0.f;
        cntI[n] = cnt;
        int c = cnt; if (c < 1) c = 1;
        rcnt[n] = 1.0f / (float)c;
    }
}

// ---------- device-wide exclusive scan of cntI -> ptr (3 small kernels) ----------

__global__ __launch_bounds__(256) void k_scan_a(const int* __restrict__ cntI,
                                                int* __restrict__ blockSums, int N) {
    __shared__ int red[4];
    int b = blockIdx.x, t = threadIdx.x;
    int base = b * 1024 + t * 4;
    int s = 0;
    #pragma unroll
    for (int i = 0; i < 4; ++i) { int idx = base + i; if (idx < N) s += cntI[idx]; }
    #pragma unroll
    for (int off = 32; off > 0; off >>= 1) s += __shfl_down(s, off);
    if ((t & 63) == 0) red[t >> 6] = s;
    __syncthreads();
    if (t == 0) blockSums[b] = red[0] + red[1] + red[2] + red[3];
}

__global__ __launch_bounds__(1024) void k_scan_b(int* __restrict__ blockSums, int B,
                                                 int* __restrict__ ptr, int N) {
    __shared__ int sh[1024];
    int t = threadIdx.x;
    sh[t] = (t < B) ? blockSums[t] : 0;
    __syncthreads();
    for (int off = 1; off < 1024; off <<= 1) {
        int v = (t >= off) ? sh[t - off] : 0;
        __syncthreads();
        sh[t] += v;
        __syncthreads();
    }
    if (t < B) blockSums[t] = (t == 0) ? 0 : sh[t - 1];   // exclusive
    if (t == B - 1) ptr[N] = sh[t];                        // total
}

__global__ __launch_bounds__(256) void k_scan_c(const int* __restrict__ cntI,
                                                const int* __restrict__ blockSums,
                                                int* __restrict__ ptr, int N) {
    __shared__ int th[256];
    int b = blockIdx.x, t = threadIdx.x;
    int base = b * 1024 + t * 4;
    int v[4]; int s = 0;
    #pragma unroll
    for (int i = 0; i < 4; ++i) {
        int idx = base + i;
        v[i] = (idx < N) ? cntI[idx] : 0;
        s += v[i];
    }
    th[t] = s;
    __syncthreads();
    for (int off = 1; off < 256; off <<= 1) {
        int x = (t >= off) ? th[t - off] : 0;
        __syncthreads();
        th[t] += x;
        __syncthreads();
    }
    int pre = ((t == 0) ? 0 : th[t - 1]) + blockSums[b];
    #pragma unroll
    for (int i = 0; i < 4; ++i) {
        int idx = base + i;
        if (idx < N) ptr[idx] = pre;
        pre += v[i];
    }
}

// ---------- CSR build: single pass, ONE 8B record per edge ----------
// record: w0 = row(17b) | eid[14:0]<<17 ; w1 = eid[20:15] | fp16(norm)<<16
__global__ void k_scatter(const int* __restrict__ row, const int* __restrict__ col,
                          const float* __restrict__ attr, const float* __restrict__ dinv,
                          const int* __restrict__ colptr, int* __restrict__ cursor,
                          uint2* __restrict__ csrX, int E) {
    int e = blockIdx.x * blockDim.x + threadIdx.x;
    if (e < E) {
        int r = row[e], c = col[e];
        float nrm = dinv[r] * attr[e] * dinv[c];
        unsigned short nb = __half_as_ushort(__float2half(nrm));
        unsigned int w0 = (unsigned)r | (((unsigned)e & 0x7FFFu) << 17);
        unsigned int w1 = ((unsigned)e >> 15) | ((unsigned)nb << 16);
        int pos = colptr[c] + atomicAdd(&cursor[c], 1);
        csrX[pos] = make_uint2(w0, w1);
    }
}

// ---------- encoder (fp16 h) ----------

__global__ void k_encode(const float* __restrict__ x, const float* __restrict__ w_enc,
                         const float* __restrict__ b_enc, __half* __restrict__ h, int N) {
    int idx = blockIdx.x * blockDim.x + threadIdx.x;
    if (idx < N * L) {
        int n = idx >> 6, f = idx & 63;
        h[idx] = __float2half(x[n] * w_enc[f] + b_enc[f]);
    }
}

// ---------- fused GCN layer (fp16 h storage, fp32 accumulate) ----------
// wave per node, 4 groups x 16 lanes. Metadata loaded DIRECTLY per group
// (group-uniform address -> L1 broadcast) -- no staging shfls on the DS pipe.

__global__ __launch_bounds__(256) void k_gcn(const uint2* __restrict__ h_in2,
        __half* __restrict__ h_out,
        const float* __restrict__ W, const float* __restrict__ bias,
        const int* __restrict__ colptr, const uint2* __restrict__ csrX,
        const float* __restrict__ rcnt, int N) {
    __shared__ float sm[4][72];        // 4 waves x 64 floats (+pad)
    int lane = threadIdx.x & 63;
    int warp = threadIdx.x >> 6;
    int grp  = lane >> 4;
    int sub  = lane & 15;
    int wid  = (blockIdx.x * blockDim.x + threadIdx.x) >> 6;
    int nw   = (gridDim.x * blockDim.x) >> 6;
    float* smw = &sm[warp][0];

    float Wc[L];                       // column `lane` of W
    #pragma unroll
    for (int f = 0; f < L; ++f) Wc[f] = W[f * L + lane];
    float bl = bias[lane];

    for (int n = wid; n < N; n += nw) {
        int beg = colptr[n], end = colptr[n + 1];
        float4 sA = make_float4(0.f, 0.f, 0.f, 0.f);
        float4 sB = make_float4(0.f, 0.f, 0.f, 0.f);
        float4 sC = make_float4(0.f, 0.f, 0.f, 0.f);
        float4 sD = make_float4(0.f, 0.f, 0.f, 0.f);
        int j = beg + grp;
        for (; j + 12 < end; j += 16) {
            uint2 m0 = csrX[j];
            uint2 m1 = csrX[j + 4];
            uint2 m2 = csrX[j + 8];
            uint2 m3 = csrX[j + 12];
            int r0 = (int)(m0.x & 0x1FFFFu), r1 = (int)(m1.x & 0x1FFFFu);
            int r2 = (int)(m2.x & 0x1FFFFu), r3 = (int)(m3.x & 0x1FFFFu);
            float w0 = __half2float(__ushort_as_half((unsigned short)(m0.y >> 16)));
            float w1 = __half2float(__ushort_as_half((unsigned short)(m1.y >> 16)));
            float w2 = __half2float(__ushort_as_half((unsigned short)(m2.y >> 16)));
            float w3 = __half2float(__ushort_as_half((unsigned short)(m3.y >> 16)));
            uint2 q0 = h_in2[(size_t)r0 * 16 + sub];
            uint2 q1 = h_in2[(size_t)r1 * 16 + sub];
            uint2 q2 = h_in2[(size_t)r2 * 16 + sub];
            uint2 q3 = h_in2[(size_t)r3 * 16 + sub];
            float2 l0 = __half22float2(*(__half2*)&q0.x), g0 = __half22float2(*(__half2*)&q0.y);
            float2 l1 = __half22float2(*(__half2*)&q1.x), g1 = __half22float2(*(__half2*)&q1.y);
            float2 l2 = __half22float2(*(__half2*)&q2.x), g2 = __half22float2(*(__half2*)&q2.y);
            float2 l3 = __half22float2(*(__half2*)&q3.x), g3 = __half22float2(*(__half2*)&q3.y);
            sA.x += w0 * l0.x; sA.y += w0 * l0.y; sA.z += w0 * g0.x; sA.w += w0 * g0.y;
            sB.x += w1 * l1.x; sB.y += w1 * l1.y; sB.z += w1 * g1.x; sB.w += w1 * g1.y;
            sC.x += w2 * l2.x; sC.y += w2 * l2.y; sC.z += w2 * g2.x; sC.w += w2 * g2.y;
            sD.x += w3 * l3.x; sD.y += w3 * l3.y; sD.z += w3 * g3.x; sD.w += w3 * g3.y;
        }
        for (; j < end; j += 4) {
            uint2 m0 = csrX[j];
            int   r0 = (int)(m0.x & 0x1FFFFu);
            float w0 = __half2float(__ushort_as_half((unsigned short)(m0.y >> 16)));
            uint2 q0 = h_in2[(size_t)r0 * 16 + sub];
            float2 l0 = __half22float2(*(__half2*)&q0.x), g0 = __half22float2(*(__half2*)&q0.y);
            sA.x += w0 * l0.x; sA.y += w0 * l0.y; sA.z += w0 * g0.x; sA.w += w0 * g0.y;
        }
        float4 s;
        s.x = (sA.x + sB.x) + (sC.x + sD.x);
        s.y = (sA.y + sB.y) + (sC.y + sD.y);
        s.z = (sA.z + sB.z) + (sC.z + sD.z);
        s.w = (sA.w + sB.w) + (sC.w + sD.w);
        // combine the 4 edge-groups
        s.x += __shfl_xor(s.x, 16); s.x += __shfl_xor(s.x, 32);
        s.y += __shfl_xor(s.y, 16); s.y += __shfl_xor(s.y, 32);
        s.z += __shfl_xor(s.z, 16); s.z += __shfl_xor(s.z, 32);
        s.w += __shfl_xor(s.w, 16); s.w += __shfl_xor(s.w, 32);
        // stage s (features 4*sub..4*sub+3 live at lane sub) into LDS
        if (grp == 0) {
            smw[4 * sub + 0] = s.x; smw[4 * sub + 1] = s.y;
            smw[4 * sub + 2] = s.z; smw[4 * sub + 3] = s.w;
        }
        __builtin_amdgcn_s_waitcnt(WAITCNT_LGKM0);  // wave-internal LDS RAW fence
        // matvec via uniform-address (broadcast) b128 reads
        float a0 = 0.f, a1 = 0.f, a2 = 0.f, a3 = 0.f;
        const float4* smv = (const float4*)smw;
        #pragma unroll
        for (int q = 0; q < 16; ++q) {
            float4 sv = smv[q];
            a0 += sv.x * Wc[4 * q + 0];
            a1 += sv.y * Wc[4 * q + 1];
            a2 += sv.z * Wc[4 * q + 2];
            a3 += sv.w * Wc[4 * q + 3];
        }
        float o = ((a0 + a1) + (a2 + a3)) * rcnt[n] + bl;
        h_out[(size_t)n * L + lane] = __float2half(fmaxf(o, 0.f));
    }
}

// ---------- fused decoder node matvecs: U = h@W1[:64]+b1, V = h@W1[64:] (fp16 out) ----------

__global__ __launch_bounds__(256) void k_mv2(const __half* __restrict__ h,
        const float* __restrict__ W1, const float* __restrict__ b1,
        __half* __restrict__ U, __half* __restrict__ V, int N) {
    __shared__ float sm[4][72];
    int lane = threadIdx.x & 63;
    int warp = threadIdx.x >> 6;
    int wid  = (blockIdx.x * blockDim.x + threadIdx.x) >> 6;
    int nw   = (gridDim.x * blockDim.x) >> 6;
    float* smw = &sm[warp][0];
    float Wu[L], Wv[L];
    #pragma unroll
    for (int f = 0; f < L; ++f) Wu[f] = W1[f * L + lane];
    #pragma unroll
    for (int f = 0; f < L; ++f) Wv[f] = W1[(L + f) * L + lane];
    float bl = b1[lane];
    for (int n = wid; n < N; n += nw) {
        float hl = __half2float(h[(size_t)n * L + lane]);
        smw[lane] = hl;
        __builtin_amdgcn_s_waitcnt(WAITCNT_LGKM0);
        float a0 = 0.f, a1 = 0.f, c0 = 0.f, c1 = 0.f;
        const float4* smv = (const float4*)smw;
        #pragma unroll
        for (int q = 0; q < 16; ++q) {
            float4 sv = smv[q];
            a0 += sv.x * Wu[4 * q + 0] ; a1 += sv.y * Wu[4 * q + 1];
            a0 += sv.z * Wu[4 * q + 2] ; a1 += sv.w * Wu[4 * q + 3];
            c0 += sv.x * Wv[4 * q + 0] ; c1 += sv.y * Wv[4 * q + 1];
            c0 += sv.z * Wv[4 * q + 2] ; c1 += sv.w * Wv[4 * q + 3];
        }
        U[(size_t)n * L + lane] = __float2half((a0 + a1) + bl);
        V[(size_t)n * L + lane] = __float2half(c0 + c1);
        __builtin_amdgcn_s_waitcnt(WAITCNT_LGKM0);  // WAR guard before next store
    }
}

// ---------- decoder edge pass: wave per node, TWO lanes per edge ----------
// each lane computes 32 features (its 64B half-row of U/V); 1 shfl per edge.

__global__ __launch_bounds__(256) void k_edge(const __half* __restrict__ U,
        const __half* __restrict__ V, const float* __restrict__ w2,
        const float* __restrict__ b2,
        const int* __restrict__ colptr, const uint2* __restrict__ csrX,
        float* __restrict__ out, int N) {
    int lane = threadIdx.x & 63;
    int half = lane & 1;               // feature half: [32*half, 32*half+32)
    int wid  = (blockIdx.x * blockDim.x + threadIdx.x) >> 6;
    int nw   = (gridDim.x * blockDim.x) >> 6;
    float w2f[32];
    #pragma unroll
    for (int k = 0; k < 32; ++k) w2f[k] = w2[32 * half + k];
    float b2v = b2[0];

    for (int n = wid; n < N; n += nw) {
        int beg = colptr[n], end = colptr[n + 1];
        const uint4* vrow = (const uint4*)(V + (size_t)n * L + 32 * half);
        uint4 v0 = vrow[0], v1 = vrow[1], v2 = vrow[2], v3 = vrow[3];
        for (int base = beg; base < end; base += 32) {
            int epos = base + (lane >> 1);
            if (epos < end) {
                uint2 md = csrX[epos];
                int r  = (int)(md.x & 0x1FFFFu);
                int ei = (int)((md.x >> 17) | ((md.y & 0x3Fu) << 15));
                const uint4* urow = (const uint4*)(U + (size_t)r * L + 32 * half);
                uint4 u0 = urow[0], u1 = urow[1], u2 = urow[2], u3 = urow[3];
                float p = 0.f;
                #define DOT8(uq, vq, B) { \
                    __half2 ta = h2relu(h2add(*(__half2*)&(uq).x, *(__half2*)&(vq).x)); \
                    __half2 tb = h2relu(h2add(*(__half2*)&(uq).y, *(__half2*)&(vq).y)); \
                    __half2 tc = h2relu(h2add(*(__half2*)&(uq).z, *(__half2*)&(vq).z)); \
                    __half2 td = h2relu(h2add(*(__half2*)&(uq).w, *(__half2*)&(vq).w)); \
                    float2 fa = __half22float2(ta), fb = __half22float2(tb); \
                    float2 fc = __half22float2(tc), fd = __half22float2(td); \
                    p += fa.x * w2f[B+0] + fa.y * w2f[B+1] + fb.x * w2f[B+2] + fb.y * w2f[B+3]; \
                    p += fc.x * w2f[B+4] + fc.y * w2f[B+5] + fd.x * w2f[B+6] + fd.y * w2f[B+7]; }
                DOT8(u0, v0, 0) DOT8(u1, v1, 8) DOT8(u2, v2, 16) DOT8(u3, v3, 24)
                #undef DOT8
                p += __shfl_xor(p, 1);     // combine the two halves
                if (half == 0) {
                    float val = p + b2v;
                    if (r == n) val = fmaxf(val, 0.f) + log1pf(expf(-fabsf(val)));
                    out[ei] = val;
                }
            }
        }
    }
}

// ---------- launch ----------

extern "C" void kernel_launch(void* const* d_in, const int* in_sizes, int n_in,
                              void* d_out, int out_size, void* d_ws, size_t ws_size,
                              hipStream_t stream) {
    const float* x     = (const float*)d_in[0];
    const float* attr  = (const float*)d_in[1];
    const float* w_enc = (const float*)d_in[2];
    const float* b_enc = (const float*)d_in[3];
    const float* c1w   = (const float*)d_in[4];
    const float* c1b   = (const float*)d_in[5];
    const float* c2w   = (const float*)d_in[6];
    const float* c2b   = (const float*)d_in[7];
    const float* dw1   = (const float*)d_in[8];
    const float* db1   = (const float*)d_in[9];
    const float* dw2   = (const float*)d_in[10];
    const float* db2   = (const float*)d_in[11];
    const int*   erow  = (const int*)d_in[12];
    const int*   ecol  = (const int*)d_in[13];
    int N = in_sizes[0];
    int E = in_sizes[1];
    float* out = (float*)d_out;

    char* w = (char*)d_ws;
    auto alloc = [&](size_t bytes) {
        char* p = w; w += (bytes + 255) & ~(size_t)255; return p;
    };
    unsigned long long* degcnt = (unsigned long long*)alloc((size_t)N * 8);  // zeroed
    int*   cursor = (int*)  alloc((size_t)N * 4);                            // zeroed
    size_t zbytes = (size_t)(w - (char*)d_ws);
    float* dinv   = (float*)alloc((size_t)N * 4);
    int*   cntI   = (int*)  alloc((size_t)N * 4);
    float* rcnt   = (float*)alloc((size_t)N * 4);
    int*   colptr = (int*)  alloc((size_t)(N + 1) * 4);
    int*   bsums  = (int*)  alloc(((size_t)(N + 1023) / 1024 + 1) * 4);
    uint2* csrX   = (uint2*)alloc((size_t)E * 8);
    __half* hA    = (__half*)alloc((size_t)N * L * 2);   // fp16 h ping
    __half* hB    = (__half*)alloc((size_t)N * L * 2);   // fp16 h pong
    __half* hU    = (__half*)alloc((size_t)N * L * 2);   // decoder U (fp16)
    __half* hV    = (__half*)alloc((size_t)N * L * 2);   // decoder V (fp16)
    (void)ws_size; (void)n_in; (void)out_size;

    (void)hipMemsetAsync(d_ws, 0, zbytes, stream);

    int eb = (E + 255) / 256;
    int nb = (N + 255) / 256;
    int B  = (N + 1023) / 1024;     // scan chunks
    k_hist<<<eb, 256, 0, stream>>>(ecol, attr, degcnt, E);
    k_dinv<<<nb, 256, 0, stream>>>(degcnt, dinv, cntI, rcnt, N);
    k_scan_a<<<B, 256, 0, stream>>>(cntI, bsums, N);
    k_scan_b<<<1, 1024, 0, stream>>>(bsums, B, colptr, N);
    k_scan_c<<<B, 256, 0, stream>>>(cntI, bsums, colptr, N);
    k_scatter<<<eb, 256, 0, stream>>>(erow, ecol, attr, dinv, colptr, cursor, csrX, E);
    k_encode<<<(N * L + 255) / 256, 256, 0, stream>>>(x, w_enc, b_enc, hA, N);

    __half* hin = hA; __half* hout = hB;
    for (int i = 0; i < 3; ++i) {
        k_gcn<<<2048, 256, 0, stream>>>((const uint2*)hin, hout, c1w + i * L * L,
                                        c1b + i * L, colptr, csrX, rcnt, N);
        __half* t = hin; hin = hout; hout = t;
        k_gcn<<<2048, 256, 0, stream>>>((const uint2*)hin, hout, c2w + i * L * L,
                                        c2b + i * L, colptr, csrX, rcnt, N);
        t = hin; hin = hout; hout = t;
    }
    // final h in hA (fp16). U -> hU (with b1 folded), V -> hV
    k_mv2<<<2048, 256, 0, stream>>>(hin, dw1, db1, hU, hV, N);
    k_edge<<<2048, 256, 0, stream>>>(hU, hV, dw2, db2, colptr, csrX, out, N);
}

// Round 12
// 770.555 us; speedup vs baseline: 1.0326x; 1.0326x over previous
//
#include <hip/hip_runtime.h>
#include <hip/hip_fp16.h>
#include <math.h>

#define L 64
#define FIXS 1048576.0f   // 2^20 fixed-point scale for attr histogram
#define WAITCNT_LGKM0 0xC07F   // vmcnt=63, expcnt=7, lgkmcnt=0

typedef _Float16 half8 __attribute__((ext_vector_type(8)));
typedef float f32x4 __attribute__((ext_vector_type(4)));

// packed-half helpers with pinned types (avoids bf16-header overload ambiguity)
static __device__ __forceinline__ __half2 h2add(__half2 a, __half2 b) {
    return __half2{__hadd(a.x, b.x), __hadd(a.y, b.y)};
}
static __device__ __forceinline__ __half2 h2relu(__half2 a) {
    const __half z = __float2half(0.f);
    return __half2{__hgt(a.x, z) ? a.x : z, __hgt(a.y, z) ? a.y : z};
}

// ---------- preprocessing ----------

__global__ void k_hist(const int* __restrict__ col, const float* __restrict__ attr,
                       unsigned long long* __restrict__ degcnt, int E) {
    int e = blockIdx.x * blockDim.x + threadIdx.x;
    if (e < E) {
        int c = col[e];
        unsigned int fx = (unsigned int)(int)rintf(attr[e] * FIXS);
        atomicAdd(&degcnt[c], (1ULL << 32) | (unsigned long long)fx);
    }
}

__global__ void k_dinv(const unsigned long long* __restrict__ degcnt,
                       float* __restrict__ dinv, int* __restrict__ cntI,
                       float* __restrict__ rcnt, int N) {
    int n = blockIdx.x * blockDim.x + threadIdx.x;
    if (n < N) {
        unsigned long long p = degcnt[n];
        int cnt = (int)(p >> 32);
        float d = (float)(unsigned int)(p & 0xffffffffULL) * (1.0f / FIXS);
        dinv[n] = (d > 0.f) ? (1.0f / sqrtf(fmaxf(d, 1e-30f))) : 0.f;
        cntI[n] = cnt;
        int c = cnt; if (c < 1) c = 1;
        rcnt[n] = 1.0f / (float)c;
    }
}

// ---------- device-wide exclusive scan of cntI -> ptr (3 small kernels) ----------

__global__ __launch_bounds__(256) void k_scan_a(const int* __restrict__ cntI,
                                                int* __restrict__ blockSums, int N) {
    __shared__ int red[4];
    int b = blockIdx.x, t = threadIdx.x;
    int base = b * 1024 + t * 4;
    int s = 0;
    #pragma unroll
    for (int i = 0; i < 4; ++i) { int idx = base + i; if (idx < N) s += cntI[idx]; }
    #pragma unroll
    for (int off = 32; off > 0; off >>= 1) s += __shfl_down(s, off);
    if ((t & 63) == 0) red[t >> 6] = s;
    __syncthreads();
    if (t == 0) blockSums[b] = red[0] + red[1] + red[2] + red[3];
}

__global__ __launch_bounds__(1024) void k_scan_b(int* __restrict__ blockSums, int B,
                                                 int* __restrict__ ptr, int N) {
    __shared__ int sh[1024];
    int t = threadIdx.x;
    sh[t] = (t < B) ? blockSums[t] : 0;
    __syncthreads();
    for (int off = 1; off < 1024; off <<= 1) {
        int v = (t >= off) ? sh[t - off] : 0;
        __syncthreads();
        sh[t] += v;
        __syncthreads();
    }
    if (t < B) blockSums[t] = (t == 0) ? 0 : sh[t - 1];   // exclusive
    if (t == B - 1) ptr[N] = sh[t];                        // total
}

__global__ __launch_bounds__(256) void k_scan_c(const int* __restrict__ cntI,
                                                const int* __restrict__ blockSums,
                                                int* __restrict__ ptr, int N) {
    __shared__ int th[256];
    int b = blockIdx.x, t = threadIdx.x;
    int base = b * 1024 + t * 4;
    int v[4]; int s = 0;
    #pragma unroll
    for (int i = 0; i < 4; ++i) {
        int idx = base + i;
        v[i] = (idx < N) ? cntI[idx] : 0;
        s += v[i];
    }
    th[t] = s;
    __syncthreads();
    for (int off = 1; off < 256; off <<= 1) {
        int x = (t >= off) ? th[t - off] : 0;
        __syncthreads();
        th[t] += x;
        __syncthreads();
    }
    int pre = ((t == 0) ? 0 : th[t - 1]) + blockSums[b];
    #pragma unroll
    for (int i = 0; i < 4; ++i) {
        int idx = base + i;
        if (idx < N) ptr[idx] = pre;
        pre += v[i];
    }
}

// ---------- CSR build: single pass, ONE 8B record per edge ----------
// record: w0 = row(17b) | eid[14:0]<<17 ; w1 = eid[20:15] | fp16(norm)<<16
__global__ void k_scatter(const int* __restrict__ row, const int* __restrict__ col,
                          const float* __restrict__ attr, const float* __restrict__ dinv,
                          const int* __restrict__ colptr, int* __restrict__ cursor,
                          uint2* __restrict__ csrX, int E) {
    int e = blockIdx.x * blockDim.x + threadIdx.x;
    if (e < E) {
        int r = row[e], c = col[e];
        float nrm = dinv[r] * attr[e] * dinv[c];
        unsigned short nb = __half_as_ushort(__float2half(nrm));
        unsigned int w0 = (unsigned)r | (((unsigned)e & 0x7FFFu) << 17);
        unsigned int w1 = ((unsigned)e >> 15) | ((unsigned)nb << 16);
        int pos = colptr[c] + atomicAdd(&cursor[c], 1);
        csrX[pos] = make_uint2(w0, w1);
    }
}

// ---------- encoder (fp16 h) ----------

__global__ void k_encode(const float* __restrict__ x, const float* __restrict__ w_enc,
                         const float* __restrict__ b_enc, __half* __restrict__ h, int N) {
    int idx = blockIdx.x * blockDim.x + threadIdx.x;
    if (idx < N * L) {
        int n = idx >> 6, f = idx & 63;
        h[idx] = __float2half(x[n] * w_enc[f] + b_enc[f]);
    }
}

// ---------- fused GCN layer ----------
// Wave handles 16 nodes. Per node: R10 staged-metadata + shfl broadcast gather
// (4 groups x 4 rows in flight), pair-combine (4 shfls), stage 2 fp16 partial
// blocks in LDS. Then one batched MFMA matvec: D[16n x 64f] = S[16 x 128] @ W'
// (K-stacked partials; W reused for both K-blocks). Removes the per-node
// 16x ds_read_b128 matvec + 64 VALU FMAs.

__global__ __launch_bounds__(256) void k_gcn(const uint2* __restrict__ h_in2,
        __half* __restrict__ h_out,
        const float* __restrict__ W, const float* __restrict__ bias,
        const int* __restrict__ colptr, const uint2* __restrict__ csrX,
        const float* __restrict__ rcnt, int N) {
    // per-wave tile: [p(2)][node(16)][72 halves] (row stride 72 breaks banks)
    __shared__ unsigned short smt[4][2304];
    int lane = threadIdx.x & 63;
    int warp = threadIdx.x >> 6;
    int grp  = lane >> 4;          // quad
    int sub  = lane & 15;
    int wid  = (blockIdx.x * blockDim.x + threadIdx.x) >> 6;
    int nw   = (gridDim.x * blockDim.x) >> 6;
    unsigned short* tile = &smt[warp][0];

    // B fragments: B[k][n], k = u*32 + grp*8 + j, n = sub + 16*t  (fp16)
    half8 bf[4][2];
    #pragma unroll
    for (int t = 0; t < 4; ++t)
        #pragma unroll
        for (int u = 0; u < 2; ++u)
            #pragma unroll
            for (int j = 0; j < 8; ++j)
                bf[t][u][j] = (_Float16)W[(u * 32 + grp * 8 + j) * L + sub + 16 * t];
    float bl[4];
    #pragma unroll
    for (int t = 0; t < 4; ++t) bl[t] = bias[sub + 16 * t];

    int ngroups = (N + 15) >> 4;
    for (int g = wid; g < ngroups; g += nw) {
        int nbase = g << 4;
        // ---- aggregate 16 nodes, staging fp16 partials ----
        for (int nl = 0; nl < 16; ++nl) {
            int n = nbase + nl;
            float4 sA = make_float4(0.f, 0.f, 0.f, 0.f);
            float4 sB = make_float4(0.f, 0.f, 0.f, 0.f);
            float4 sC = make_float4(0.f, 0.f, 0.f, 0.f);
            float4 sD = make_float4(0.f, 0.f, 0.f, 0.f);
            if (n < N) {
                int beg = colptr[n], end = colptr[n + 1];
                for (int cb = beg; cb < end; cb += 64) {
                    int m = end - cb; if (m > 64) m = 64;
                    int rm = 0, wb = 0;
                    if (lane < m) {
                        uint2 md = csrX[cb + lane];
                        rm = (int)(md.x & 0x1FFFFu);
                        wb = __float_as_int(__half2float(__ushort_as_half((unsigned short)(md.y >> 16))));
                    }
                    int kmax = (m + 3) >> 2;
                    int k = 0;
                    for (; k + 4 <= kmax; k += 4) {
                        int j0 = 4 * k + grp;
                        int   r0 = __shfl(rm, j0),      r1 = __shfl(rm, j0 + 4);
                        int   r2 = __shfl(rm, j0 + 8),  r3 = __shfl(rm, j0 + 12);
                        float w0 = __int_as_float(__shfl(wb, j0));
                        float w1 = __int_as_float(__shfl(wb, j0 + 4));
                        float w2 = __int_as_float(__shfl(wb, j0 + 8));
                        float w3 = __int_as_float(__shfl(wb, j0 + 12));
                        uint2 q0 = h_in2[(size_t)r0 * 16 + sub];
                        uint2 q1 = h_in2[(size_t)r1 * 16 + sub];
                        uint2 q2 = h_in2[(size_t)r2 * 16 + sub];
                        uint2 q3 = h_in2[(size_t)r3 * 16 + sub];
                        float2 l0 = __half22float2(*(__half2*)&q0.x), g0 = __half22float2(*(__half2*)&q0.y);
                        float2 l1 = __half22float2(*(__half2*)&q1.x), g1 = __half22float2(*(__half2*)&q1.y);
                        float2 l2 = __half22float2(*(__half2*)&q2.x), g2 = __half22float2(*(__half2*)&q2.y);
                        float2 l3 = __half22float2(*(__half2*)&q3.x), g3 = __half22float2(*(__half2*)&q3.y);
                        sA.x += w0 * l0.x; sA.y += w0 * l0.y; sA.z += w0 * g0.x; sA.w += w0 * g0.y;
                        sB.x += w1 * l1.x; sB.y += w1 * l1.y; sB.z += w1 * g1.x; sB.w += w1 * g1.y;
                        sC.x += w2 * l2.x; sC.y += w2 * l2.y; sC.z += w2 * g2.x; sC.w += w2 * g2.y;
                        sD.x += w3 * l3.x; sD.y += w3 * l3.y; sD.z += w3 * g3.x; sD.w += w3 * g3.y;
                    }
                    for (; k < kmax; ++k) {
                        int j0 = 4 * k + grp;
                        int   r0 = __shfl(rm, j0);
                        float w0 = __int_as_float(__shfl(wb, j0));
                        uint2 q0 = h_in2[(size_t)r0 * 16 + sub];
                        float2 l0 = __half22float2(*(__half2*)&q0.x), g0 = __half22float2(*(__half2*)&q0.y);
                        sA.x += w0 * l0.x; sA.y += w0 * l0.y; sA.z += w0 * g0.x; sA.w += w0 * g0.y;
                    }
                }
            }
            float4 s;
            s.x = (sA.x + sB.x) + (sC.x + sD.x);
            s.y = (sA.y + sB.y) + (sC.y + sD.y);
            s.z = (sA.z + sB.z) + (sC.z + sD.z);
            s.w = (sA.w + sB.w) + (sC.w + sD.w);
            // pair-combine: quads {0,1} -> partial p0, quads {2,3} -> partial p1
            s.x += __shfl_xor(s.x, 16);
            s.y += __shfl_xor(s.y, 16);
            s.z += __shfl_xor(s.z, 16);
            s.w += __shfl_xor(s.w, 16);
            if ((grp & 1) == 0) {
                int p = grp >> 1;
                __half2 lo; lo.x = __float2half(s.x); lo.y = __float2half(s.y);
                __half2 hi; hi.x = __float2half(s.z); hi.y = __float2half(s.w);
                uint2 pk = make_uint2(*(unsigned*)&lo, *(unsigned*)&hi);
                *(uint2*)&tile[p * 1152 + nl * 72 + sub * 4] = pk;
            }
        }
        __builtin_amdgcn_s_waitcnt(WAITCNT_LGKM0);  // staging visible to reads
        // ---- batched MFMA matvec: K = 128 (2 partial blocks x 64 feats) ----
        f32x4 acc[4] = {f32x4{0,0,0,0}, f32x4{0,0,0,0}, f32x4{0,0,0,0}, f32x4{0,0,0,0}};
        #pragma unroll
        for (int s = 0; s < 4; ++s) {
            int p = s >> 1;
            half8 a = *(half8*)&tile[p * 1152 + sub * 72 + (s & 1) * 32 + grp * 8];
            #pragma unroll
            for (int t = 0; t < 4; ++t)
                acc[t] = __builtin_amdgcn_mfma_f32_16x16x32_f16(a, bf[t][s & 1], acc[t], 0, 0, 0);
        }
        // ---- epilogue: D[row=quad*4+reg][col=sub] ; node = nbase+row, feat = sub+16t
        float rc[4];
        #pragma unroll
        for (int r = 0; r < 4; ++r) {
            int node = nbase + grp * 4 + r;
            rc[r] = (node < N) ? rcnt[node] : 0.f;
        }
        #pragma unroll
        for (int t = 0; t < 4; ++t)
            #pragma unroll
            for (int r = 0; r < 4; ++r) {
                int node = nbase + grp * 4 + r;
                if (node < N) {
                    float o = acc[t][r] * rc[r] + bl[t];
                    h_out[(size_t)node * L + sub + 16 * t] = __float2half(fmaxf(o, 0.f));
                }
            }
        __builtin_amdgcn_s_waitcnt(WAITCNT_LGKM0);  // WAR guard before next batch
    }
}

// ---------- fused decoder node matvecs: U = h@W1[:64]+b1, V = h@W1[64:] (fp16 out) ----------

__global__ __launch_bounds__(256) void k_mv2(const __half* __restrict__ h,
        const float* __restrict__ W1, const float* __restrict__ b1,
        __half* __restrict__ U, __half* __restrict__ V, int N) {
    __shared__ float sm[4][72];
    int lane = threadIdx.x & 63;
    int warp = threadIdx.x >> 6;
    int wid  = (blockIdx.x * blockDim.x + threadIdx.x) >> 6;
    int nw   = (gridDim.x * blockDim.x) >> 6;
    float* smw = &sm[warp][0];
    float Wu[L], Wv[L];
    #pragma unroll
    for (int f = 0; f < L; ++f) Wu[f] = W1[f * L + lane];
    #pragma unroll
    for (int f = 0; f < L; ++f) Wv[f] = W1[(L + f) * L + lane];
    float bl = b1[lane];
    for (int n = wid; n < N; n += nw) {
        float hl = __half2float(h[(size_t)n * L + lane]);
        smw[lane] = hl;
        __builtin_amdgcn_s_waitcnt(WAITCNT_LGKM0);
        float a0 = 0.f, a1 = 0.f, c0 = 0.f, c1 = 0.f;
        const float4* smv = (const float4*)smw;
        #pragma unroll
        for (int q = 0; q < 16; ++q) {
            float4 sv = smv[q];
            a0 += sv.x * Wu[4 * q + 0] ; a1 += sv.y * Wu[4 * q + 1];
            a0 += sv.z * Wu[4 * q + 2] ; a1 += sv.w * Wu[4 * q + 3];
            c0 += sv.x * Wv[4 * q + 0] ; c1 += sv.y * Wv[4 * q + 1];
            c0 += sv.z * Wv[4 * q + 2] ; c1 += sv.w * Wv[4 * q + 3];
        }
        U[(size_t)n * L + lane] = __float2half((a0 + a1) + bl);
        V[(size_t)n * L + lane] = __float2half(c0 + c1);
        __builtin_amdgcn_s_waitcnt(WAITCNT_LGKM0);  // WAR guard before next store
    }
}

// ---------- decoder edge pass: wave per node, TWO lanes per edge ----------

__global__ __launch_bounds__(256) void k_edge(const __half* __restrict__ U,
        const __half* __restrict__ V, const float* __restrict__ w2,
        const float* __restrict__ b2,
        const int* __restrict__ colptr, const uint2* __restrict__ csrX,
        float* __restrict__ out, int N) {
    int lane = threadIdx.x & 63;
    int half = lane & 1;               // feature half: [32*half, 32*half+32)
    int wid  = (blockIdx.x * blockDim.x + threadIdx.x) >> 6;
    int nw   = (gridDim.x * blockDim.x) >> 6;
    float w2f[32];
    #pragma unroll
    for (int k = 0; k < 32; ++k) w2f[k] = w2[32 * half + k];
    float b2v = b2[0];

    for (int n = wid; n < N; n += nw) {
        int beg = colptr[n], end = colptr[n + 1];
        const uint4* vrow = (const uint4*)(V + (size_t)n * L + 32 * half);
        uint4 v0 = vrow[0], v1 = vrow[1], v2 = vrow[2], v3 = vrow[3];
        for (int base = beg; base < end; base += 32) {
            int epos = base + (lane >> 1);
            if (epos < end) {
                uint2 md = csrX[epos];
                int r  = (int)(md.x & 0x1FFFFu);
                int ei = (int)((md.x >> 17) | ((md.y & 0x3Fu) << 15));
                const uint4* urow = (const uint4*)(U + (size_t)r * L + 32 * half);
                uint4 u0 = urow[0], u1 = urow[1], u2 = urow[2], u3 = urow[3];
                float p = 0.f;
                #define DOT8(uq, vq, B) { \
                    __half2 ta = h2relu(h2add(*(__half2*)&(uq).x, *(__half2*)&(vq).x)); \
                    __half2 tb = h2relu(h2add(*(__half2*)&(uq).y, *(__half2*)&(vq).y)); \
                    __half2 tc = h2relu(h2add(*(__half2*)&(uq).z, *(__half2*)&(vq).z)); \
                    __half2 td = h2relu(h2add(*(__half2*)&(uq).w, *(__half2*)&(vq).w)); \
                    float2 fa = __half22float2(ta), fb = __half22float2(tb); \
                    float2 fc = __half22float2(tc), fd = __half22float2(td); \
                    p += fa.x * w2f[B+0] + fa.y * w2f[B+1] + fb.x * w2f[B+2] + fb.y * w2f[B+3]; \
                    p += fc.x * w2f[B+4] + fc.y * w2f[B+5] + fd.x * w2f[B+6] + fd.y * w2f[B+7]; }
                DOT8(u0, v0, 0) DOT8(u1, v1, 8) DOT8(u2, v2, 16) DOT8(u3, v3, 24)
                #undef DOT8
                p += __shfl_xor(p, 1);     // combine the two halves
                if (half == 0) {
                    float val = p + b2v;
                    if (r == n) val = fmaxf(val, 0.f) + log1pf(expf(-fabsf(val)));
                    out[ei] = val;
                }
            }
        }
    }
}

// ---------- launch ----------

extern "C" void kernel_launch(void* const* d_in, const int* in_sizes, int n_in,
                              void* d_out, int out_size, void* d_ws, size_t ws_size,
                              hipStream_t stream) {
    const float* x     = (const float*)d_in[0];
    const float* attr  = (const float*)d_in[1];
    const float* w_enc = (const float*)d_in[2];
    const float* b_enc = (const float*)d_in[3];
    const float* c1w   = (const float*)d_in[4];
    const float* c1b   = (const float*)d_in[5];
    const float* c2w   = (const float*)d_in[6];
    const float* c2b   = (const float*)d_in[7];
    const float* dw1   = (const float*)d_in[8];
    const float* db1   = (const float*)d_in[9];
    const float* dw2   = (const float*)d_in[10];
    const float* db2   = (const float*)d_in[11];
    const int*   erow  = (const int*)d_in[12];
    const int*   ecol  = (const int*)d_in[13];
    int N = in_sizes[0];
    int E = in_sizes[1];
    float* out = (float*)d_out;

    char* w = (char*)d_ws;
    auto alloc = [&](size_t bytes) {
        char* p = w; w += (bytes + 255) & ~(size_t)255; return p;
    };
    unsigned long long* degcnt = (unsigned long long*)alloc((size_t)N * 8);  // zeroed
    int*   cursor = (int*)  alloc((size_t)N * 4);                            // zeroed
    size_t zbytes = (size_t)(w - (char*)d_ws);
    float* dinv   = (float*)alloc((size_t)N * 4);
    int*   cntI   = (int*)  alloc((size_t)N * 4);
    float* rcnt   = (float*)alloc((size_t)N * 4);
    int*   colptr = (int*)  alloc((size_t)(N + 1) * 4);
    int*   bsums  = (int*)  alloc(((size_t)(N + 1023) / 1024 + 1) * 4);
    uint2* csrX   = (uint2*)alloc((size_t)E * 8);
    __half* hA    = (__half*)alloc((size_t)N * L * 2);   // fp16 h ping
    __half* hB    = (__half*)alloc((size_t)N * L * 2);   // fp16 h pong
    __half* hU    = (__half*)alloc((size_t)N * L * 2);   // decoder U (fp16)
    __half* hV    = (__half*)alloc((size_t)N * L * 2);   // decoder V (fp16)
    (void)ws_size; (void)n_in; (void)out_size;

    (void)hipMemsetAsync(d_ws, 0, zbytes, stream);

    int eb = (E + 255) / 256;
    int nb = (N + 255) / 256;
    int B  = (N + 1023) / 1024;     // scan chunks
    k_hist<<<eb, 256, 0, stream>>>(ecol, attr, degcnt, E);
    k_dinv<<<nb, 256, 0, stream>>>(degcnt, dinv, cntI, rcnt, N);
    k_scan_a<<<B, 256, 0, stream>>>(cntI, bsums, N);
    k_scan_b<<<1, 1024, 0, stream>>>(bsums, B, colptr, N);
    k_scan_c<<<B, 256, 0, stream>>>(cntI, bsums, colptr, N);
    k_scatter<<<eb, 256, 0, stream>>>(erow, ecol, attr, dinv, colptr, cursor, csrX, E);
    k_encode<<<(N * L + 255) / 256, 256, 0, stream>>>(x, w_enc, b_enc, hA, N);

    __half* hin = hA; __half* hout = hB;
    for (int i = 0; i < 3; ++i) {
        k_gcn<<<2048, 256, 0, stream>>>((const uint2*)hin, hout, c1w + i * L * L,
                                        c1b + i * L, colptr, csrX, rcnt, N);
        __half* t = hin; hin = hout; hout = t;
        k_gcn<<<2048, 256, 0, stream>>>((const uint2*)hin, hout, c2w + i * L * L,
                                        c2b + i * L, colptr, csrX, rcnt, N);
        t = hin; hin = hout; hout = t;
    }
    // final h in hA (fp16). U -> hU (with b1 folded), V -> hV
    k_mv2<<<2048, 256, 0, stream>>>(hin, dw1, db1, hU, hV, N);
    k_edge<<<2048, 256, 0, stream>>>(hU, hV, dw2, db2, colptr, csrX, out, N);
}

// Round 13
// 762.472 us; speedup vs baseline: 1.0435x; 1.0106x over previous
//
#include <hip/hip_runtime.h>
#include <hip/hip_fp16.h>
#include <math.h>

#define L 64
#define FIXS 1048576.0f   // 2^20 fixed-point scale for attr histogram
#define WAITCNT_LGKM0 0xC07F   // vmcnt=63, expcnt=7, lgkmcnt=0

typedef _Float16 half8 __attribute__((ext_vector_type(8)));
typedef float f32x4 __attribute__((ext_vector_type(4)));

// packed-half helpers with pinned types (avoids bf16-header overload ambiguity)
static __device__ __forceinline__ __half2 h2add(__half2 a, __half2 b) {
    return __half2{__hadd(a.x, b.x), __hadd(a.y, b.y)};
}
static __device__ __forceinline__ __half2 h2relu(__half2 a) {
    const __half z = __float2half(0.f);
    return __half2{__hgt(a.x, z) ? a.x : z, __hgt(a.y, z) ? a.y : z};
}

// ---------- preprocessing ----------

__global__ void k_hist(const int* __restrict__ col, const float* __restrict__ attr,
                       unsigned long long* __restrict__ degcnt, int E) {
    int e = blockIdx.x * blockDim.x + threadIdx.x;
    if (e < E) {
        int c = col[e];
        unsigned int fx = (unsigned int)(int)rintf(attr[e] * FIXS);
        atomicAdd(&degcnt[c], (1ULL << 32) | (unsigned long long)fx);
    }
}

__global__ void k_dinv(const unsigned long long* __restrict__ degcnt,
                       float* __restrict__ dinv, int* __restrict__ cntI,
                       float* __restrict__ rcnt, int N) {
    int n = blockIdx.x * blockDim.x + threadIdx.x;
    if (n < N) {
        unsigned long long p = degcnt[n];
        int cnt = (int)(p >> 32);
        float d = (float)(unsigned int)(p & 0xffffffffULL) * (1.0f / FIXS);
        dinv[n] = (d > 0.f) ? (1.0f / sqrtf(fmaxf(d, 1e-30f))) : 0.f;
        cntI[n] = cnt;
        int c = cnt; if (c < 1) c = 1;
        rcnt[n] = 1.0f / (float)c;
    }
}

// ---------- device-wide exclusive scan of cntI -> ptr (3 small kernels) ----------

__global__ __launch_bounds__(256) void k_scan_a(const int* __restrict__ cntI,
                                                int* __restrict__ blockSums, int N) {
    __shared__ int red[4];
    int b = blockIdx.x, t = threadIdx.x;
    int base = b * 1024 + t * 4;
    int s = 0;
    #pragma unroll
    for (int i = 0; i < 4; ++i) { int idx = base + i; if (idx < N) s += cntI[idx]; }
    #pragma unroll
    for (int off = 32; off > 0; off >>= 1) s += __shfl_down(s, off);
    if ((t & 63) == 0) red[t >> 6] = s;
    __syncthreads();
    if (t == 0) blockSums[b] = red[0] + red[1] + red[2] + red[3];
}

__global__ __launch_bounds__(1024) void k_scan_b(int* __restrict__ blockSums, int B,
                                                 int* __restrict__ ptr, int N) {
    __shared__ int sh[1024];
    int t = threadIdx.x;
    sh[t] = (t < B) ? blockSums[t] : 0;
    __syncthreads();
    for (int off = 1; off < 1024; off <<= 1) {
        int v = (t >= off) ? sh[t - off] : 0;
        __syncthreads();
        sh[t] += v;
        __syncthreads();
    }
    if (t < B) blockSums[t] = (t == 0) ? 0 : sh[t - 1];   // exclusive
    if (t == B - 1) ptr[N] = sh[t];                        // total
}

__global__ __launch_bounds__(256) void k_scan_c(const int* __restrict__ cntI,
                                                const int* __restrict__ blockSums,
                                                int* __restrict__ ptr, int N) {
    __shared__ int th[256];
    int b = blockIdx.x, t = threadIdx.x;
    int base = b * 1024 + t * 4;
    int v[4]; int s = 0;
    #pragma unroll
    for (int i = 0; i < 4; ++i) {
        int idx = base + i;
        v[i] = (idx < N) ? cntI[idx] : 0;
        s += v[i];
    }
    th[t] = s;
    __syncthreads();
    for (int off = 1; off < 256; off <<= 1) {
        int x = (t >= off) ? th[t - off] : 0;
        __syncthreads();
        th[t] += x;
        __syncthreads();
    }
    int pre = ((t == 0) ? 0 : th[t - 1]) + blockSums[b];
    #pragma unroll
    for (int i = 0; i < 4; ++i) {
        int idx = base + i;
        if (idx < N) ptr[idx] = pre;
        pre += v[i];
    }
}

// ---------- CSR build: single pass, ONE 8B record per edge ----------
// record: w0 = row(17b) | eid[14:0]<<17 ; w1 = eid[20:15] | fp16(norm)<<16
__global__ void k_scatter(const int* __restrict__ row, const int* __restrict__ col,
                          const float* __restrict__ attr, const float* __restrict__ dinv,
                          const int* __restrict__ colptr, int* __restrict__ cursor,
                          uint2* __restrict__ csrX, int E) {
    int e = blockIdx.x * blockDim.x + threadIdx.x;
    if (e < E) {
        int r = row[e], c = col[e];
        float nrm = dinv[r] * attr[e] * dinv[c];
        unsigned short nb = __half_as_ushort(__float2half(nrm));
        unsigned int w0 = (unsigned)r | (((unsigned)e & 0x7FFFu) << 17);
        unsigned int w1 = ((unsigned)e >> 15) | ((unsigned)nb << 16);
        int pos = colptr[c] + atomicAdd(&cursor[c], 1);
        csrX[pos] = make_uint2(w0, w1);
    }
}

// ---------- encoder (fp16 h) ----------

__global__ void k_encode(const float* __restrict__ x, const float* __restrict__ w_enc,
                         const float* __restrict__ b_enc, __half* __restrict__ h, int N) {
    int idx = blockIdx.x * blockDim.x + threadIdx.x;
    if (idx < N * L) {
        int n = idx >> 6, f = idx & 63;
        h[idx] = __float2half(x[n] * w_enc[f] + b_enc[f]);
    }
}

// ---------- fused GCN layer ----------
// Wave handles 16 nodes, INTERLEAVED across the index range (node = g + j*ngroups)
// so every wave carries ~mean degree work (degree is index-skewed: col=min(r,c)).
// Per node: staged-metadata + shfl broadcast gather, pair-combine, stage 2 fp16
// partial blocks in LDS. One batched MFMA matvec per 16 nodes:
// D[16n x 64f] = S[16 x 128] @ W' (K-stacked partials, W reused per K-block).

__global__ __launch_bounds__(256) void k_gcn(const uint2* __restrict__ h_in2,
        __half* __restrict__ h_out,
        const float* __restrict__ W, const float* __restrict__ bias,
        const int* __restrict__ colptr, const uint2* __restrict__ csrX,
        const float* __restrict__ rcnt, int N) {
    // per-wave tile: [p(2)][noderow(16)][72 halves] (stride 72 breaks banks)
    __shared__ unsigned short smt[4][2304];
    int lane = threadIdx.x & 63;
    int warp = threadIdx.x >> 6;
    int grp  = lane >> 4;          // quad
    int sub  = lane & 15;
    int wid  = (blockIdx.x * blockDim.x + threadIdx.x) >> 6;
    int nw   = (gridDim.x * blockDim.x) >> 6;
    unsigned short* tile = &smt[warp][0];

    // B fragments: B[k][n], k = u*32 + grp*8 + j, n = sub + 16*t  (fp16)
    half8 bf[4][2];
    #pragma unroll
    for (int t = 0; t < 4; ++t)
        #pragma unroll
        for (int u = 0; u < 2; ++u)
            #pragma unroll
            for (int j = 0; j < 8; ++j)
                bf[t][u][j] = (_Float16)W[(u * 32 + grp * 8 + j) * L + sub + 16 * t];
    float bl[4];
    #pragma unroll
    for (int t = 0; t < 4; ++t) bl[t] = bias[sub + 16 * t];

    int ngroups = (N + 15) >> 4;
    for (int g = wid; g < ngroups; g += nw) {
        // ---- aggregate 16 interleaved nodes, staging fp16 partials ----
        for (int nl = 0; nl < 16; ++nl) {
            int n = g + nl * ngroups;
            float4 sA = make_float4(0.f, 0.f, 0.f, 0.f);
            float4 sB = make_float4(0.f, 0.f, 0.f, 0.f);
            float4 sC = make_float4(0.f, 0.f, 0.f, 0.f);
            float4 sD = make_float4(0.f, 0.f, 0.f, 0.f);
            if (n < N) {
                int beg = colptr[n], end = colptr[n + 1];
                for (int cb = beg; cb < end; cb += 64) {
                    int m = end - cb; if (m > 64) m = 64;
                    int rm = 0, wb = 0;
                    if (lane < m) {
                        uint2 md = csrX[cb + lane];
                        rm = (int)(md.x & 0x1FFFFu);
                        wb = __float_as_int(__half2float(__ushort_as_half((unsigned short)(md.y >> 16))));
                    }
                    int kmax = (m + 3) >> 2;
                    int k = 0;
                    for (; k + 4 <= kmax; k += 4) {
                        int j0 = 4 * k + grp;
                        int   r0 = __shfl(rm, j0),      r1 = __shfl(rm, j0 + 4);
                        int   r2 = __shfl(rm, j0 + 8),  r3 = __shfl(rm, j0 + 12);
                        float w0 = __int_as_float(__shfl(wb, j0));
                        float w1 = __int_as_float(__shfl(wb, j0 + 4));
                        float w2 = __int_as_float(__shfl(wb, j0 + 8));
                        float w3 = __int_as_float(__shfl(wb, j0 + 12));
                        uint2 q0 = h_in2[(size_t)r0 * 16 + sub];
                        uint2 q1 = h_in2[(size_t)r1 * 16 + sub];
                        uint2 q2 = h_in2[(size_t)r2 * 16 + sub];
                        uint2 q3 = h_in2[(size_t)r3 * 16 + sub];
                        float2 l0 = __half22float2(*(__half2*)&q0.x), g0 = __half22float2(*(__half2*)&q0.y);
                        float2 l1 = __half22float2(*(__half2*)&q1.x), g1 = __half22float2(*(__half2*)&q1.y);
                        float2 l2 = __half22float2(*(__half2*)&q2.x), g2 = __half22float2(*(__half2*)&q2.y);
                        float2 l3 = __half22float2(*(__half2*)&q3.x), g3 = __half22float2(*(__half2*)&q3.y);
                        sA.x += w0 * l0.x; sA.y += w0 * l0.y; sA.z += w0 * g0.x; sA.w += w0 * g0.y;
                        sB.x += w1 * l1.x; sB.y += w1 * l1.y; sB.z += w1 * g1.x; sB.w += w1 * g1.y;
                        sC.x += w2 * l2.x; sC.y += w2 * l2.y; sC.z += w2 * g2.x; sC.w += w2 * g2.y;
                        sD.x += w3 * l3.x; sD.y += w3 * l3.y; sD.z += w3 * g3.x; sD.w += w3 * g3.y;
                    }
                    for (; k < kmax; ++k) {
                        int j0 = 4 * k + grp;
                        int   r0 = __shfl(rm, j0);
                        float w0 = __int_as_float(__shfl(wb, j0));
                        uint2 q0 = h_in2[(size_t)r0 * 16 + sub];
                        float2 l0 = __half22float2(*(__half2*)&q0.x), g0 = __half22float2(*(__half2*)&q0.y);
                        sA.x += w0 * l0.x; sA.y += w0 * l0.y; sA.z += w0 * g0.x; sA.w += w0 * g0.y;
                    }
                }
            }
            float4 s;
            s.x = (sA.x + sB.x) + (sC.x + sD.x);
            s.y = (sA.y + sB.y) + (sC.y + sD.y);
            s.z = (sA.z + sB.z) + (sC.z + sD.z);
            s.w = (sA.w + sB.w) + (sC.w + sD.w);
            // pair-combine: quads {0,1} -> partial p0, quads {2,3} -> partial p1
            s.x += __shfl_xor(s.x, 16);
            s.y += __shfl_xor(s.y, 16);
            s.z += __shfl_xor(s.z, 16);
            s.w += __shfl_xor(s.w, 16);
            if ((grp & 1) == 0) {
                int p = grp >> 1;
                __half2 lo; lo.x = __float2half(s.x); lo.y = __float2half(s.y);
                __half2 hi; hi.x = __float2half(s.z); hi.y = __float2half(s.w);
                uint2 pk = make_uint2(*(unsigned*)&lo, *(unsigned*)&hi);
                *(uint2*)&tile[p * 1152 + nl * 72 + sub * 4] = pk;
            }
        }
        __builtin_amdgcn_s_waitcnt(WAITCNT_LGKM0);  // staging visible to reads
        // ---- batched MFMA matvec: K = 128 (2 partial blocks x 64 feats) ----
        f32x4 acc[4] = {f32x4{0,0,0,0}, f32x4{0,0,0,0}, f32x4{0,0,0,0}, f32x4{0,0,0,0}};
        #pragma unroll
        for (int s = 0; s < 4; ++s) {
            int p = s >> 1;
            half8 a = *(half8*)&tile[p * 1152 + sub * 72 + (s & 1) * 32 + grp * 8];
            #pragma unroll
            for (int t = 0; t < 4; ++t)
                acc[t] = __builtin_amdgcn_mfma_f32_16x16x32_f16(a, bf[t][s & 1], acc[t], 0, 0, 0);
        }
        // ---- epilogue: D[row=quad*4+reg][col=sub] ; node = g + row*ngroups
        float rc[4];
        #pragma unroll
        for (int r = 0; r < 4; ++r) {
            int node = g + (grp * 4 + r) * ngroups;
            rc[r] = (node < N) ? rcnt[node] : 0.f;
        }
        #pragma unroll
        for (int t = 0; t < 4; ++t)
            #pragma unroll
            for (int r = 0; r < 4; ++r) {
                int node = g + (grp * 4 + r) * ngroups;
                if (node < N) {
                    float o = acc[t][r] * rc[r] + bl[t];
                    h_out[(size_t)node * L + sub + 16 * t] = __float2half(fmaxf(o, 0.f));
                }
            }
        __builtin_amdgcn_s_waitcnt(WAITCNT_LGKM0);  // WAR guard before next batch
    }
}

// ---------- fused decoder node matvecs: U = h@W1[:64]+b1, V = h@W1[64:] (fp16 out) ----------

__global__ __launch_bounds__(256) void k_mv2(const __half* __restrict__ h,
        const float* __restrict__ W1, const float* __restrict__ b1,
        __half* __restrict__ U, __half* __restrict__ V, int N) {
    __shared__ float sm[4][72];
    int lane = threadIdx.x & 63;
    int warp = threadIdx.x >> 6;
    int wid  = (blockIdx.x * blockDim.x + threadIdx.x) >> 6;
    int nw   = (gridDim.x * blockDim.x) >> 6;
    float* smw = &sm[warp][0];
    float Wu[L], Wv[L];
    #pragma unroll
    for (int f = 0; f < L; ++f) Wu[f] = W1[f * L + lane];
    #pragma unroll
    for (int f = 0; f < L; ++f) Wv[f] = W1[(L + f) * L + lane];
    float bl = b1[lane];
    for (int n = wid; n < N; n += nw) {
        float hl = __half2float(h[(size_t)n * L + lane]);
        smw[lane] = hl;
        __builtin_amdgcn_s_waitcnt(WAITCNT_LGKM0);
        float a0 = 0.f, a1 = 0.f, c0 = 0.f, c1 = 0.f;
        const float4* smv = (const float4*)smw;
        #pragma unroll
        for (int q = 0; q < 16; ++q) {
            float4 sv = smv[q];
            a0 += sv.x * Wu[4 * q + 0] ; a1 += sv.y * Wu[4 * q + 1];
            a0 += sv.z * Wu[4 * q + 2] ; a1 += sv.w * Wu[4 * q + 3];
            c0 += sv.x * Wv[4 * q + 0] ; c1 += sv.y * Wv[4 * q + 1];
            c0 += sv.z * Wv[4 * q + 2] ; c1 += sv.w * Wv[4 * q + 3];
        }
        U[(size_t)n * L + lane] = __float2half((a0 + a1) + bl);
        V[(size_t)n * L + lane] = __float2half(c0 + c1);
        __builtin_amdgcn_s_waitcnt(WAITCNT_LGKM0);  // WAR guard before next store
    }
}

// ---------- decoder edge pass: wave per node, TWO lanes per edge ----------

__global__ __launch_bounds__(256) void k_edge(const __half* __restrict__ U,
        const __half* __restrict__ V, const float* __restrict__ w2,
        const float* __restrict__ b2,
        const int* __restrict__ colptr, const uint2* __restrict__ csrX,
        float* __restrict__ out, int N) {
    int lane = threadIdx.x & 63;
    int half = lane & 1;               // feature half: [32*half, 32*half+32)
    int wid  = (blockIdx.x * blockDim.x + threadIdx.x) >> 6;
    int nw   = (gridDim.x * blockDim.x) >> 6;
    float w2f[32];
    #pragma unroll
    for (int k = 0; k < 32; ++k) w2f[k] = w2[32 * half + k];
    float b2v = b2[0];

    for (int n = wid; n < N; n += nw) {
        int beg = colptr[n], end = colptr[n + 1];
        const uint4* vrow = (const uint4*)(V + (size_t)n * L + 32 * half);
        uint4 v0 = vrow[0], v1 = vrow[1], v2 = vrow[2], v3 = vrow[3];
        for (int base = beg; base < end; base += 32) {
            int epos = base + (lane >> 1);
            if (epos < end) {
                uint2 md = csrX[epos];
                int r  = (int)(md.x & 0x1FFFFu);
                int ei = (int)((md.x >> 17) | ((md.y & 0x3Fu) << 15));
                const uint4* urow = (const uint4*)(U + (size_t)r * L + 32 * half);
                uint4 u0 = urow[0], u1 = urow[1], u2 = urow[2], u3 = urow[3];
                float p = 0.f;
                #define DOT8(uq, vq, B) { \
                    __half2 ta = h2relu(h2add(*(__half2*)&(uq).x, *(__half2*)&(vq).x)); \
                    __half2 tb = h2relu(h2add(*(__half2*)&(uq).y, *(__half2*)&(vq).y)); \
                    __half2 tc = h2relu(h2add(*(__half2*)&(uq).z, *(__half2*)&(vq).z)); \
                    __half2 td = h2relu(h2add(*(__half2*)&(uq).w, *(__half2*)&(vq).w)); \
                    float2 fa = __half22float2(ta), fb = __half22float2(tb); \
                    float2 fc = __half22float2(tc), fd = __half22float2(td); \
                    p += fa.x * w2f[B+0] + fa.y * w2f[B+1] + fb.x * w2f[B+2] + fb.y * w2f[B+3]; \
                    p += fc.x * w2f[B+4] + fc.y * w2f[B+5] + fd.x * w2f[B+6] + fd.y * w2f[B+7]; }
                DOT8(u0, v0, 0) DOT8(u1, v1, 8) DOT8(u2, v2, 16) DOT8(u3, v3, 24)
                #undef DOT8
                p += __shfl_xor(p, 1);     // combine the two halves
                if (half == 0) {
                    float val = p + b2v;
                    if (r == n) val = fmaxf(val, 0.f) + log1pf(expf(-fabsf(val)));
                    out[ei] = val;
                }
            }
        }
    }
}

// ---------- launch ----------

extern "C" void kernel_launch(void* const* d_in, const int* in_sizes, int n_in,
                              void* d_out, int out_size, void* d_ws, size_t ws_size,
                              hipStream_t stream) {
    const float* x     = (const float*)d_in[0];
    const float* attr  = (const float*)d_in[1];
    const float* w_enc = (const float*)d_in[2];
    const float* b_enc = (const float*)d_in[3];
    const float* c1w   = (const float*)d_in[4];
    const float* c1b   = (const float*)d_in[5];
    const float* c2w   = (const float*)d_in[6];
    const float* c2b   = (const float*)d_in[7];
    const float* dw1   = (const float*)d_in[8];
    const float* db1   = (const float*)d_in[9];
    const float* dw2   = (const float*)d_in[10];
    const float* db2   = (const float*)d_in[11];
    const int*   erow  = (const int*)d_in[12];
    const int*   ecol  = (const int*)d_in[13];
    int N = in_sizes[0];
    int E = in_sizes[1];
    float* out = (float*)d_out;

    char* w = (char*)d_ws;
    auto alloc = [&](size_t bytes) {
        char* p = w; w += (bytes + 255) & ~(size_t)255; return p;
    };
    unsigned long long* degcnt = (unsigned long long*)alloc((size_t)N * 8);  // zeroed
    int*   cursor = (int*)  alloc((size_t)N * 4);                            // zeroed
    size_t zbytes = (size_t)(w - (char*)d_ws);
    float* dinv   = (float*)alloc((size_t)N * 4);
    int*   cntI   = (int*)  alloc((size_t)N * 4);
    float* rcnt   = (float*)alloc((size_t)N * 4);
    int*   colptr = (int*)  alloc((size_t)(N + 1) * 4);
    int*   bsums  = (int*)  alloc(((size_t)(N + 1023) / 1024 + 1) * 4);
    uint2* csrX   = (uint2*)alloc((size_t)E * 8);
    __half* hA    = (__half*)alloc((size_t)N * L * 2);   // fp16 h ping
    __half* hB    = (__half*)alloc((size_t)N * L * 2);   // fp16 h pong
    __half* hU    = (__half*)alloc((size_t)N * L * 2);   // decoder U (fp16)
    __half* hV    = (__half*)alloc((size_t)N * L * 2);   // decoder V (fp16)
    (void)ws_size; (void)n_in; (void)out_size;

    (void)hipMemsetAsync(d_ws, 0, zbytes, stream);

    int eb = (E + 255) / 256;
    int nb = (N + 255) / 256;
    int B  = (N + 1023) / 1024;     // scan chunks
    int ngroups = (N + 15) / 16;
    int gcnBlocks = (ngroups + 3) / 4 + 8;   // ~1 group per wave, all co-resident
    k_hist<<<eb, 256, 0, stream>>>(ecol, attr, degcnt, E);
    k_dinv<<<nb, 256, 0, stream>>>(degcnt, dinv, cntI, rcnt, N);
    k_scan_a<<<B, 256, 0, stream>>>(cntI, bsums, N);
    k_scan_b<<<1, 1024, 0, stream>>>(bsums, B, colptr, N);
    k_scan_c<<<B, 256, 0, stream>>>(cntI, bsums, colptr, N);
    k_scatter<<<eb, 256, 0, stream>>>(erow, ecol, attr, dinv, colptr, cursor, csrX, E);
    k_encode<<<(N * L + 255) / 256, 256, 0, stream>>>(x, w_enc, b_enc, hA, N);

    __half* hin = hA; __half* hout = hB;
    for (int i = 0; i < 3; ++i) {
        k_gcn<<<gcnBlocks, 256, 0, stream>>>((const uint2*)hin, hout, c1w + i * L * L,
                                             c1b + i * L, colptr, csrX, rcnt, N);
        __half* t = hin; hin = hout; hout = t;
        k_gcn<<<gcnBlocks, 256, 0, stream>>>((const uint2*)hin, hout, c2w + i * L * L,
                                             c2b + i * L, colptr, csrX, rcnt, N);
        t = hin; hin = hout; hout = t;
    }
    // final h in hA (fp16). U -> hU (with b1 folded), V -> hV
    k_mv2<<<2048, 256, 0, stream>>>(hin, dw1, db1, hU, hV, N);
    k_edge<<<2048, 256, 0, stream>>>(hU, hV, dw2, db2, colptr, csrX, out, N);
}

// Round 14
// 715.937 us; speedup vs baseline: 1.1113x; 1.0650x over previous
//
#include <hip/hip_runtime.h>
#include <hip/hip_fp16.h>
#include <math.h>

#define L 64
#define FIXS 1048576.0f   // 2^20 fixed-point scale for attr histogram
#define WAITCNT_LGKM0 0xC07F   // vmcnt=63, expcnt=7, lgkmcnt=0

// packed-half helpers with pinned types (avoids bf16-header overload ambiguity)
static __device__ __forceinline__ __half2 h2add(__half2 a, __half2 b) {
    return __half2{__hadd(a.x, b.x), __hadd(a.y, b.y)};
}
static __device__ __forceinline__ __half2 h2relu(__half2 a) {
    const __half z = __float2half(0.f);
    return __half2{__hgt(a.x, z) ? a.x : z, __hgt(a.y, z) ? a.y : z};
}

// ---------- preprocessing ----------

__global__ void k_hist(const int* __restrict__ col, const float* __restrict__ attr,
                       unsigned long long* __restrict__ degcnt, int E) {
    int e = blockIdx.x * blockDim.x + threadIdx.x;
    if (e < E) {
        int c = col[e];
        unsigned int fx = (unsigned int)(int)rintf(attr[e] * FIXS);
        atomicAdd(&degcnt[c], (1ULL << 32) | (unsigned long long)fx);
    }
}

__global__ void k_dinv(const unsigned long long* __restrict__ degcnt,
                       float* __restrict__ dinv, int* __restrict__ cntI,
                       float* __restrict__ rcnt, int N) {
    int n = blockIdx.x * blockDim.x + threadIdx.x;
    if (n < N) {
        unsigned long long p = degcnt[n];
        int cnt = (int)(p >> 32);
        float d = (float)(unsigned int)(p & 0xffffffffULL) * (1.0f / FIXS);
        dinv[n] = (d > 0.f) ? (1.0f / sqrtf(fmaxf(d, 1e-30f))) : 0.f;
        cntI[n] = cnt;
        int c = cnt; if (c < 1) c = 1;
        rcnt[n] = 1.0f / (float)c;
    }
}

// ---------- device-wide exclusive scan of cntI -> ptr (3 small kernels) ----------

__global__ __launch_bounds__(256) void k_scan_a(const int* __restrict__ cntI,
                                                int* __restrict__ blockSums, int N) {
    __shared__ int red[4];
    int b = blockIdx.x, t = threadIdx.x;
    int base = b * 1024 + t * 4;
    int s = 0;
    #pragma unroll
    for (int i = 0; i < 4; ++i) { int idx = base + i; if (idx < N) s += cntI[idx]; }
    #pragma unroll
    for (int off = 32; off > 0; off >>= 1) s += __shfl_down(s, off);
    if ((t & 63) == 0) red[t >> 6] = s;
    __syncthreads();
    if (t == 0) blockSums[b] = red[0] + red[1] + red[2] + red[3];
}

__global__ __launch_bounds__(1024) void k_scan_b(int* __restrict__ blockSums, int B,
                                                 int* __restrict__ ptr, int N) {
    __shared__ int sh[1024];
    int t = threadIdx.x;
    sh[t] = (t < B) ? blockSums[t] : 0;
    __syncthreads();
    for (int off = 1; off < 1024; off <<= 1) {
        int v = (t >= off) ? sh[t - off] : 0;
        __syncthreads();
        sh[t] += v;
        __syncthreads();
    }
    if (t < B) blockSums[t] = (t == 0) ? 0 : sh[t - 1];   // exclusive
    if (t == B - 1) ptr[N] = sh[t];                        // total
}

__global__ __launch_bounds__(256) void k_scan_c(const int* __restrict__ cntI,
                                                const int* __restrict__ blockSums,
                                                int* __restrict__ ptr, int N) {
    __shared__ int th[256];
    int b = blockIdx.x, t = threadIdx.x;
    int base = b * 1024 + t * 4;
    int v[4]; int s = 0;
    #pragma unroll
    for (int i = 0; i < 4; ++i) {
        int idx = base + i;
        v[i] = (idx < N) ? cntI[idx] : 0;
        s += v[i];
    }
    th[t] = s;
    __syncthreads();
    for (int off = 1; off < 256; off <<= 1) {
        int x = (t >= off) ? th[t - off] : 0;
        __syncthreads();
        th[t] += x;
        __syncthreads();
    }
    int pre = ((t == 0) ? 0 : th[t - 1]) + blockSums[b];
    #pragma unroll
    for (int i = 0; i < 4; ++i) {
        int idx = base + i;
        if (idx < N) ptr[idx] = pre;
        pre += v[i];
    }
}

// ---------- CSR build: single pass, ONE 8B record per edge ----------
// record: w0 = row(17b) | fp16(norm) sans sign (15b) << 17 ; w1 = eid
// (norm > 0 always, so dropping the fp16 sign bit is lossless)
__global__ void k_scatter(const int* __restrict__ row, const int* __restrict__ col,
                          const float* __restrict__ attr, const float* __restrict__ dinv,
                          const int* __restrict__ colptr, int* __restrict__ cursor,
                          uint2* __restrict__ csrX, int E) {
    int e = blockIdx.x * blockDim.x + threadIdx.x;
    if (e < E) {
        int r = row[e], c = col[e];
        float nrm = dinv[r] * attr[e] * dinv[c];
        unsigned short nb = __half_as_ushort(__float2half(nrm));   // sign bit = 0
        unsigned int w0 = (unsigned)r | ((unsigned)nb << 17);
        int pos = colptr[c] + atomicAdd(&cursor[c], 1);
        csrX[pos] = make_uint2(w0, (unsigned)e);
    }
}

// ---------- encoder (fp16 h) ----------

__global__ void k_encode(const float* __restrict__ x, const float* __restrict__ w_enc,
                         const float* __restrict__ b_enc, __half* __restrict__ h, int N) {
    int idx = blockIdx.x * blockDim.x + threadIdx.x;
    if (idx < N * L) {
        int n = idx >> 6, f = idx & 63;
        h[idx] = __float2half(x[n] * w_enc[f] + b_enc[f]);
    }
}

// ---------- fused GCN layer (R10 structure + single-shfl metadata) ----------
// wave per node (strided for balance); 4 x 16-lane groups each gather an 8B
// fp16 slice of a different edge's h_in row (16 rows in flight, unroll 4).
// Metadata: ONE word per edge (row|norm15), ONE shfl per edge. Matvec epilogue
// via LDS broadcast (16 uniform-address b128 reads).

__global__ __launch_bounds__(256) void k_gcn(const uint2* __restrict__ h_in2,
        __half* __restrict__ h_out,
        const float* __restrict__ W, const float* __restrict__ bias,
        const int* __restrict__ colptr, const uint2* __restrict__ csrX,
        const float* __restrict__ rcnt, int N) {
    __shared__ float sm[4][72];        // 4 waves x 64 floats (+pad)
    int lane = threadIdx.x & 63;
    int warp = threadIdx.x >> 6;
    int grp  = lane >> 4;
    int sub  = lane & 15;
    int wid  = (blockIdx.x * blockDim.x + threadIdx.x) >> 6;
    int nw   = (gridDim.x * blockDim.x) >> 6;
    float* smw = &sm[warp][0];
    const unsigned* csrw = (const unsigned*)csrX;   // word 0 of each record

    float Wc[L];                       // column `lane` of W
    #pragma unroll
    for (int f = 0; f < L; ++f) Wc[f] = W[f * L + lane];
    float bl = bias[lane];

    for (int n = wid; n < N; n += nw) {
        int beg = colptr[n], end = colptr[n + 1];
        float4 sA = make_float4(0.f, 0.f, 0.f, 0.f);
        float4 sB = make_float4(0.f, 0.f, 0.f, 0.f);
        float4 sC = make_float4(0.f, 0.f, 0.f, 0.f);
        float4 sD = make_float4(0.f, 0.f, 0.f, 0.f);
        for (int base = beg; base < end; base += 64) {
            int m = end - base; if (m > 64) m = 64;
            unsigned mw = 0;
            if (lane < m) mw = csrw[(size_t)(base + lane) * 2];
            int kmax = (m + 3) >> 2;
            int k = 0;
            for (; k + 4 <= kmax; k += 4) {
                int j0 = 4 * k + grp;
                unsigned x0 = (unsigned)__shfl((int)mw, j0);
                unsigned x1 = (unsigned)__shfl((int)mw, j0 + 4);
                unsigned x2 = (unsigned)__shfl((int)mw, j0 + 8);
                unsigned x3 = (unsigned)__shfl((int)mw, j0 + 12);
                int r0 = (int)(x0 & 0x1FFFFu), r1 = (int)(x1 & 0x1FFFFu);
                int r2 = (int)(x2 & 0x1FFFFu), r3 = (int)(x3 & 0x1FFFFu);
                float w0 = __half2float(__ushort_as_half((unsigned short)(x0 >> 17)));
                float w1 = __half2float(__ushort_as_half((unsigned short)(x1 >> 17)));
                float w2 = __half2float(__ushort_as_half((unsigned short)(x2 >> 17)));
                float w3 = __half2float(__ushort_as_half((unsigned short)(x3 >> 17)));
                uint2 q0 = h_in2[(size_t)r0 * 16 + sub];
                uint2 q1 = h_in2[(size_t)r1 * 16 + sub];
                uint2 q2 = h_in2[(size_t)r2 * 16 + sub];
                uint2 q3 = h_in2[(size_t)r3 * 16 + sub];
                float2 l0 = __half22float2(*(__half2*)&q0.x), g0 = __half22float2(*(__half2*)&q0.y);
                float2 l1 = __half22float2(*(__half2*)&q1.x), g1 = __half22float2(*(__half2*)&q1.y);
                float2 l2 = __half22float2(*(__half2*)&q2.x), g2 = __half22float2(*(__half2*)&q2.y);
                float2 l3 = __half22float2(*(__half2*)&q3.x), g3 = __half22float2(*(__half2*)&q3.y);
                sA.x += w0 * l0.x; sA.y += w0 * l0.y; sA.z += w0 * g0.x; sA.w += w0 * g0.y;
                sB.x += w1 * l1.x; sB.y += w1 * l1.y; sB.z += w1 * g1.x; sB.w += w1 * g1.y;
                sC.x += w2 * l2.x; sC.y += w2 * l2.y; sC.z += w2 * g2.x; sC.w += w2 * g2.y;
                sD.x += w3 * l3.x; sD.y += w3 * l3.y; sD.z += w3 * g3.x; sD.w += w3 * g3.y;
            }
            for (; k < kmax; ++k) {
                int j0 = 4 * k + grp;
                unsigned x0 = (unsigned)__shfl((int)mw, j0);
                int   r0 = (int)(x0 & 0x1FFFFu);
                float w0 = __half2float(__ushort_as_half((unsigned short)(x0 >> 17)));
                uint2 q0 = h_in2[(size_t)r0 * 16 + sub];
                float2 l0 = __half22float2(*(__half2*)&q0.x), g0 = __half22float2(*(__half2*)&q0.y);
                sA.x += w0 * l0.x; sA.y += w0 * l0.y; sA.z += w0 * g0.x; sA.w += w0 * g0.y;
            }
        }
        float4 s;
        s.x = (sA.x + sB.x) + (sC.x + sD.x);
        s.y = (sA.y + sB.y) + (sC.y + sD.y);
        s.z = (sA.z + sB.z) + (sC.z + sD.z);
        s.w = (sA.w + sB.w) + (sC.w + sD.w);
        // combine the 4 edge-groups
        s.x += __shfl_xor(s.x, 16); s.x += __shfl_xor(s.x, 32);
        s.y += __shfl_xor(s.y, 16); s.y += __shfl_xor(s.y, 32);
        s.z += __shfl_xor(s.z, 16); s.z += __shfl_xor(s.z, 32);
        s.w += __shfl_xor(s.w, 16); s.w += __shfl_xor(s.w, 32);
        // stage s (features 4*sub..4*sub+3 live at lane sub) into LDS
        if (grp == 0) {
            smw[4 * sub + 0] = s.x; smw[4 * sub + 1] = s.y;
            smw[4 * sub + 2] = s.z; smw[4 * sub + 3] = s.w;
        }
        __builtin_amdgcn_s_waitcnt(WAITCNT_LGKM0);  // wave-internal LDS RAW fence
        // matvec via uniform-address (broadcast) b128 reads
        float a0 = 0.f, a1 = 0.f, a2 = 0.f, a3 = 0.f;
        const float4* smv = (const float4*)smw;
        #pragma unroll
        for (int q = 0; q < 16; ++q) {
            float4 sv = smv[q];
            a0 += sv.x * Wc[4 * q + 0];
            a1 += sv.y * Wc[4 * q + 1];
            a2 += sv.z * Wc[4 * q + 2];
            a3 += sv.w * Wc[4 * q + 3];
        }
        float o = ((a0 + a1) + (a2 + a3)) * rcnt[n] + bl;
        h_out[(size_t)n * L + lane] = __float2half(fmaxf(o, 0.f));
    }
}

// ---------- fused decoder node matvecs: U = h@W1[:64]+b1, V = h@W1[64:] (fp16 out) ----------

__global__ __launch_bounds__(256) void k_mv2(const __half* __restrict__ h,
        const float* __restrict__ W1, const float* __restrict__ b1,
        __half* __restrict__ U, __half* __restrict__ V, int N) {
    __shared__ float sm[4][72];
    int lane = threadIdx.x & 63;
    int warp = threadIdx.x >> 6;
    int wid  = (blockIdx.x * blockDim.x + threadIdx.x) >> 6;
    int nw   = (gridDim.x * blockDim.x) >> 6;
    float* smw = &sm[warp][0];
    float Wu[L], Wv[L];
    #pragma unroll
    for (int f = 0; f < L; ++f) Wu[f] = W1[f * L + lane];
    #pragma unroll
    for (int f = 0; f < L; ++f) Wv[f] = W1[(L + f) * L + lane];
    float bl = b1[lane];
    for (int n = wid; n < N; n += nw) {
        float hl = __half2float(h[(size_t)n * L + lane]);
        smw[lane] = hl;
        __builtin_amdgcn_s_waitcnt(WAITCNT_LGKM0);
        float a0 = 0.f, a1 = 0.f, c0 = 0.f, c1 = 0.f;
        const float4* smv = (const float4*)smw;
        #pragma unroll
        for (int q = 0; q < 16; ++q) {
            float4 sv = smv[q];
            a0 += sv.x * Wu[4 * q + 0] ; a1 += sv.y * Wu[4 * q + 1];
            a0 += sv.z * Wu[4 * q + 2] ; a1 += sv.w * Wu[4 * q + 3];
            c0 += sv.x * Wv[4 * q + 0] ; c1 += sv.y * Wv[4 * q + 1];
            c0 += sv.z * Wv[4 * q + 2] ; c1 += sv.w * Wv[4 * q + 3];
        }
        U[(size_t)n * L + lane] = __float2half((a0 + a1) + bl);
        V[(size_t)n * L + lane] = __float2half(c0 + c1);
        __builtin_amdgcn_s_waitcnt(WAITCNT_LGKM0);  // WAR guard before next store
    }
}

// ---------- decoder edge pass: wave per node, TWO lanes per edge ----------

__global__ __launch_bounds__(256) void k_edge(const __half* __restrict__ U,
        const __half* __restrict__ V, const float* __restrict__ w2,
        const float* __restrict__ b2,
        const int* __restrict__ colptr, const uint2* __restrict__ csrX,
        float* __restrict__ out, int N) {
    int lane = threadIdx.x & 63;
    int half = lane & 1;               // feature half: [32*half, 32*half+32)
    int wid  = (blockIdx.x * blockDim.x + threadIdx.x) >> 6;
    int nw   = (gridDim.x * blockDim.x) >> 6;
    float w2f[32];
    #pragma unroll
    for (int k = 0; k < 32; ++k) w2f[k] = w2[32 * half + k];
    float b2v = b2[0];

    for (int n = wid; n < N; n += nw) {
        int beg = colptr[n], end = colptr[n + 1];
        const uint4* vrow = (const uint4*)(V + (size_t)n * L + 32 * half);
        uint4 v0 = vrow[0], v1 = vrow[1], v2 = vrow[2], v3 = vrow[3];
        for (int base = beg; base < end; base += 32) {
            int epos = base + (lane >> 1);
            if (epos < end) {
                uint2 md = csrX[epos];
                int r  = (int)(md.x & 0x1FFFFu);
                int ei = (int)md.y;
                const uint4* urow = (const uint4*)(U + (size_t)r * L + 32 * half);
                uint4 u0 = urow[0], u1 = urow[1], u2 = urow[2], u3 = urow[3];
                float p = 0.f;
                #define DOT8(uq, vq, B) { \
                    __half2 ta = h2relu(h2add(*(__half2*)&(uq).x, *(__half2*)&(vq).x)); \
                    __half2 tb = h2relu(h2add(*(__half2*)&(uq).y, *(__half2*)&(vq).y)); \
                    __half2 tc = h2relu(h2add(*(__half2*)&(uq).z, *(__half2*)&(vq).z)); \
                    __half2 td = h2relu(h2add(*(__half2*)&(uq).w, *(__half2*)&(vq).w)); \
                    float2 fa = __half22float2(ta), fb = __half22float2(tb); \
                    float2 fc = __half22float2(tc), fd = __half22float2(td); \
                    p += fa.x * w2f[B+0] + fa.y * w2f[B+1] + fb.x * w2f[B+2] + fb.y * w2f[B+3]; \
                    p += fc.x * w2f[B+4] + fc.y * w2f[B+5] + fd.x * w2f[B+6] + fd.y * w2f[B+7]; }
                DOT8(u0, v0, 0) DOT8(u1, v1, 8) DOT8(u2, v2, 16) DOT8(u3, v3, 24)
                #undef DOT8
                p += __shfl_xor(p, 1);     // combine the two halves
                if (half == 0) {
                    float val = p + b2v;
                    if (r == n) val = fmaxf(val, 0.f) + log1pf(expf(-fabsf(val)));
                    out[ei] = val;
                }
            }
        }
    }
}

// ---------- launch ----------

extern "C" void kernel_launch(void* const* d_in, const int* in_sizes, int n_in,
                              void* d_out, int out_size, void* d_ws, size_t ws_size,
                              hipStream_t stream) {
    const float* x     = (const float*)d_in[0];
    const float* attr  = (const float*)d_in[1];
    const float* w_enc = (const float*)d_in[2];
    const float* b_enc = (const float*)d_in[3];
    const float* c1w   = (const float*)d_in[4];
    const float* c1b   = (const float*)d_in[5];
    const float* c2w   = (const float*)d_in[6];
    const float* c2b   = (const float*)d_in[7];
    const float* dw1   = (const float*)d_in[8];
    const float* db1   = (const float*)d_in[9];
    const float* dw2   = (const float*)d_in[10];
    const float* db2   = (const float*)d_in[11];
    const int*   erow  = (const int*)d_in[12];
    const int*   ecol  = (const int*)d_in[13];
    int N = in_sizes[0];
    int E = in_sizes[1];
    float* out = (float*)d_out;

    char* w = (char*)d_ws;
    auto alloc = [&](size_t bytes) {
        char* p = w; w += (bytes + 255) & ~(size_t)255; return p;
    };
    unsigned long long* degcnt = (unsigned long long*)alloc((size_t)N * 8);  // zeroed
    int*   cursor = (int*)  alloc((size_t)N * 4);                            // zeroed
    size_t zbytes = (size_t)(w - (char*)d_ws);
    float* dinv   = (float*)alloc((size_t)N * 4);
    int*   cntI   = (int*)  alloc((size_t)N * 4);
    float* rcnt   = (float*)alloc((size_t)N * 4);
    int*   colptr = (int*)  alloc((size_t)(N + 1) * 4);
    int*   bsums  = (int*)  alloc(((size_t)(N + 1023) / 1024 + 1) * 4);
    uint2* csrX   = (uint2*)alloc((size_t)E * 8);
    __half* hA    = (__half*)alloc((size_t)N * L * 2);   // fp16 h ping
    __half* hB    = (__half*)alloc((size_t)N * L * 2);   // fp16 h pong
    __half* hU    = (__half*)alloc((size_t)N * L * 2);   // decoder U (fp16)
    __half* hV    = (__half*)alloc((size_t)N * L * 2);   // decoder V (fp16)
    (void)ws_size; (void)n_in; (void)out_size;

    (void)hipMemsetAsync(d_ws, 0, zbytes, stream);

    int eb = (E + 255) / 256;
    int nb = (N + 255) / 256;
    int B  = (N + 1023) / 1024;     // scan chunks
    k_hist<<<eb, 256, 0, stream>>>(ecol, attr, degcnt, E);
    k_dinv<<<nb, 256, 0, stream>>>(degcnt, dinv, cntI, rcnt, N);
    k_scan_a<<<B, 256, 0, stream>>>(cntI, bsums, N);
    k_scan_b<<<1, 1024, 0, stream>>>(bsums, B, colptr, N);
    k_scan_c<<<B, 256, 0, stream>>>(cntI, bsums, colptr, N);
    k_scatter<<<eb, 256, 0, stream>>>(erow, ecol, attr, dinv, colptr, cursor, csrX, E);
    k_encode<<<(N * L + 255) / 256, 256, 0, stream>>>(x, w_enc, b_enc, hA, N);

    __half* hin = hA; __half* hout = hB;
    for (int i = 0; i < 3; ++i) {
        k_gcn<<<2048, 256, 0, stream>>>((const uint2*)hin, hout, c1w + i * L * L,
                                        c1b + i * L, colptr, csrX, rcnt, N);
        __half* t = hin; hin = hout; hout = t;
        k_gcn<<<2048, 256, 0, stream>>>((const uint2*)hin, hout, c2w + i * L * L,
                                        c2b + i * L, colptr, csrX, rcnt, N);
        t = hin; hin = hout; hout = t;
    }
    // final h in hA (fp16). U -> hU (with b1 folded), V -> hV
    k_mv2<<<2048, 256, 0, stream>>>(hin, dw1, db1, hU, hV, N);
    k_edge<<<2048, 256, 0, stream>>>(hU, hV, dw2, db2, colptr, csrX, out, N);
}

// Round 15
// 690.809 us; speedup vs baseline: 1.1518x; 1.0364x over previous
//
#include <hip/hip_runtime.h>
#include <hip/hip_fp16.h>
#include <math.h>

#define L 64
#define FIXS 1048576.0f   // 2^20 fixed-point scale for attr histogram
#define WAITCNT_LGKM0 0xC07F   // vmcnt=63, expcnt=7, lgkmcnt=0

// packed-half helpers with pinned types (avoids bf16-header overload ambiguity)
static __device__ __forceinline__ __half2 h2add(__half2 a, __half2 b) {
    return __half2{__hadd(a.x, b.x), __hadd(a.y, b.y)};
}
static __device__ __forceinline__ __half2 h2relu(__half2 a) {
    const __half z = __float2half(0.f);
    return __half2{__hgt(a.x, z) ? a.x : z, __hgt(a.y, z) ? a.y : z};
}

// ---------- preprocessing ----------

// returning 64-bit atomic: high word old value == this edge's rank within col
__global__ void k_hist(const int* __restrict__ col, const float* __restrict__ attr,
                       unsigned long long* __restrict__ degcnt,
                       int* __restrict__ rank, int E) {
    int e = blockIdx.x * blockDim.x + threadIdx.x;
    if (e < E) {
        int c = col[e];
        unsigned int fx = (unsigned int)(int)rintf(attr[e] * FIXS);
        unsigned long long old = atomicAdd(&degcnt[c], (1ULL << 32) | (unsigned long long)fx);
        rank[e] = (int)(old >> 32);
    }
}

__global__ void k_dinv(const unsigned long long* __restrict__ degcnt,
                       float* __restrict__ dinv, int* __restrict__ cntI,
                       float* __restrict__ rcnt, int N) {
    int n = blockIdx.x * blockDim.x + threadIdx.x;
    if (n < N) {
        unsigned long long p = degcnt[n];
        int cnt = (int)(p >> 32);
        float d = (float)(unsigned int)(p & 0xffffffffULL) * (1.0f / FIXS);
        dinv[n] = (d > 0.f) ? (1.0f / sqrtf(fmaxf(d, 1e-30f))) : 0.f;
        cntI[n] = cnt;
        int c = cnt; if (c < 1) c = 1;
        rcnt[n] = 1.0f / (float)c;
    }
}

// ---------- device-wide exclusive scan of cntI -> ptr (3 small kernels) ----------

__global__ __launch_bounds__(256) void k_scan_a(const int* __restrict__ cntI,
                                                int* __restrict__ blockSums, int N) {
    __shared__ int red[4];
    int b = blockIdx.x, t = threadIdx.x;
    int base = b * 1024 + t * 4;
    int s = 0;
    #pragma unroll
    for (int i = 0; i < 4; ++i) { int idx = base + i; if (idx < N) s += cntI[idx]; }
    #pragma unroll
    for (int off = 32; off > 0; off >>= 1) s += __shfl_down(s, off);
    if ((t & 63) == 0) red[t >> 6] = s;
    __syncthreads();
    if (t == 0) blockSums[b] = red[0] + red[1] + red[2] + red[3];
}

__global__ __launch_bounds__(1024) void k_scan_b(int* __restrict__ blockSums, int B,
                                                 int* __restrict__ ptr, int N) {
    __shared__ int sh[1024];
    int t = threadIdx.x;
    sh[t] = (t < B) ? blockSums[t] : 0;
    __syncthreads();
    for (int off = 1; off < 1024; off <<= 1) {
        int v = (t >= off) ? sh[t - off] : 0;
        __syncthreads();
        sh[t] += v;
        __syncthreads();
    }
    if (t < B) blockSums[t] = (t == 0) ? 0 : sh[t - 1];   // exclusive
    if (t == B - 1) ptr[N] = sh[t];                        // total
}

__global__ __launch_bounds__(256) void k_scan_c(const int* __restrict__ cntI,
                                                const int* __restrict__ blockSums,
                                                int* __restrict__ ptr, int N) {
    __shared__ int th[256];
    int b = blockIdx.x, t = threadIdx.x;
    int base = b * 1024 + t * 4;
    int v[4]; int s = 0;
    #pragma unroll
    for (int i = 0; i < 4; ++i) {
        int idx = base + i;
        v[i] = (idx < N) ? cntI[idx] : 0;
        s += v[i];
    }
    th[t] = s;
    __syncthreads();
    for (int off = 1; off < 256; off <<= 1) {
        int x = (t >= off) ? th[t - off] : 0;
        __syncthreads();
        th[t] += x;
        __syncthreads();
    }
    int pre = ((t == 0) ? 0 : th[t - 1]) + blockSums[b];
    #pragma unroll
    for (int i = 0; i < 4; ++i) {
        int idx = base + i;
        if (idx < N) ptr[idx] = pre;
        pre += v[i];
    }
}

// ---------- CSR build: NO atomic (rank precomputed), ONE 4B record per edge ----------
// record: row(17b) | fp16(norm) sans sign (15b) << 17  (norm > 0 -> lossless)
__global__ void k_scatter(const int* __restrict__ row, const int* __restrict__ col,
                          const float* __restrict__ attr, const float* __restrict__ dinv,
                          const int* __restrict__ colptr, const int* __restrict__ rank,
                          unsigned* __restrict__ csrX, int E) {
    int e = blockIdx.x * blockDim.x + threadIdx.x;
    if (e < E) {
        int r = row[e], c = col[e];
        float nrm = dinv[r] * attr[e] * dinv[c];
        unsigned short nb = __half_as_ushort(__float2half(nrm));   // sign bit = 0
        csrX[colptr[c] + rank[e]] = (unsigned)r | ((unsigned)nb << 17);
    }
}

// ---------- encoder (fp16 h) ----------

__global__ void k_encode(const float* __restrict__ x, const float* __restrict__ w_enc,
                         const float* __restrict__ b_enc, __half* __restrict__ h, int N) {
    int idx = blockIdx.x * blockDim.x + threadIdx.x;
    if (idx < N * L) {
        int n = idx >> 6, f = idx & 63;
        h[idx] = __float2half(x[n] * w_enc[f] + b_enc[f]);
    }
}

// ---------- fused GCN layer (fp16 h, fp32 accumulate; 4B records) ----------
// wave per node (strided for balance); 4 x 16-lane groups each gather an 8B
// fp16 slice of a different edge's h_in row (16 rows in flight, unroll 4).
// Metadata: ONE 4B word per edge, staged coalesced, ONE shfl per edge.
// Matvec epilogue via LDS broadcast (16 uniform-address b128 reads).

__global__ __launch_bounds__(256) void k_gcn(const uint2* __restrict__ h_in2,
        __half* __restrict__ h_out,
        const float* __restrict__ W, const float* __restrict__ bias,
        const int* __restrict__ colptr, const unsigned* __restrict__ csrX,
        const float* __restrict__ rcnt, int N) {
    __shared__ float sm[4][72];        // 4 waves x 64 floats (+pad)
    int lane = threadIdx.x & 63;
    int warp = threadIdx.x >> 6;
    int grp  = lane >> 4;
    int sub  = lane & 15;
    int wid  = (blockIdx.x * blockDim.x + threadIdx.x) >> 6;
    int nw   = (gridDim.x * blockDim.x) >> 6;
    float* smw = &sm[warp][0];

    float Wc[L];                       // column `lane` of W
    #pragma unroll
    for (int f = 0; f < L; ++f) Wc[f] = W[f * L + lane];
    float bl = bias[lane];

    for (int n = wid; n < N; n += nw) {
        int beg = colptr[n], end = colptr[n + 1];
        float4 sA = make_float4(0.f, 0.f, 0.f, 0.f);
        float4 sB = make_float4(0.f, 0.f, 0.f, 0.f);
        float4 sC = make_float4(0.f, 0.f, 0.f, 0.f);
        float4 sD = make_float4(0.f, 0.f, 0.f, 0.f);
        for (int base = beg; base < end; base += 64) {
            int m = end - base; if (m > 64) m = 64;
            unsigned mw = 0;
            if (lane < m) mw = csrX[base + lane];
            int kmax = (m + 3) >> 2;
            int k = 0;
            for (; k + 4 <= kmax; k += 4) {
                int j0 = 4 * k + grp;
                unsigned x0 = (unsigned)__shfl((int)mw, j0);
                unsigned x1 = (unsigned)__shfl((int)mw, j0 + 4);
                unsigned x2 = (unsigned)__shfl((int)mw, j0 + 8);
                unsigned x3 = (unsigned)__shfl((int)mw, j0 + 12);
                int r0 = (int)(x0 & 0x1FFFFu), r1 = (int)(x1 & 0x1FFFFu);
                int r2 = (int)(x2 & 0x1FFFFu), r3 = (int)(x3 & 0x1FFFFu);
                float w0 = __half2float(__ushort_as_half((unsigned short)(x0 >> 17)));
                float w1 = __half2float(__ushort_as_half((unsigned short)(x1 >> 17)));
                float w2 = __half2float(__ushort_as_half((unsigned short)(x2 >> 17)));
                float w3 = __half2float(__ushort_as_half((unsigned short)(x3 >> 17)));
                uint2 q0 = h_in2[(size_t)r0 * 16 + sub];
                uint2 q1 = h_in2[(size_t)r1 * 16 + sub];
                uint2 q2 = h_in2[(size_t)r2 * 16 + sub];
                uint2 q3 = h_in2[(size_t)r3 * 16 + sub];
                float2 l0 = __half22float2(*(__half2*)&q0.x), g0 = __half22float2(*(__half2*)&q0.y);
                float2 l1 = __half22float2(*(__half2*)&q1.x), g1 = __half22float2(*(__half2*)&q1.y);
                float2 l2 = __half22float2(*(__half2*)&q2.x), g2 = __half22float2(*(__half2*)&q2.y);
                float2 l3 = __half22float2(*(__half2*)&q3.x), g3 = __half22float2(*(__half2*)&q3.y);
                sA.x += w0 * l0.x; sA.y += w0 * l0.y; sA.z += w0 * g0.x; sA.w += w0 * g0.y;
                sB.x += w1 * l1.x; sB.y += w1 * l1.y; sB.z += w1 * g1.x; sB.w += w1 * g1.y;
                sC.x += w2 * l2.x; sC.y += w2 * l2.y; sC.z += w2 * g2.x; sC.w += w2 * g2.y;
                sD.x += w3 * l3.x; sD.y += w3 * l3.y; sD.z += w3 * g3.x; sD.w += w3 * g3.y;
            }
            for (; k < kmax; ++k) {
                int j0 = 4 * k + grp;
                unsigned x0 = (unsigned)__shfl((int)mw, j0);
                int   r0 = (int)(x0 & 0x1FFFFu);
                float w0 = __half2float(__ushort_as_half((unsigned short)(x0 >> 17)));
                uint2 q0 = h_in2[(size_t)r0 * 16 + sub];
                float2 l0 = __half22float2(*(__half2*)&q0.x), g0 = __half22float2(*(__half2*)&q0.y);
                sA.x += w0 * l0.x; sA.y += w0 * l0.y; sA.z += w0 * g0.x; sA.w += w0 * g0.y;
            }
        }
        float4 s;
        s.x = (sA.x + sB.x) + (sC.x + sD.x);
        s.y = (sA.y + sB.y) + (sC.y + sD.y);
        s.z = (sA.z + sB.z) + (sC.z + sD.z);
        s.w = (sA.w + sB.w) + (sC.w + sD.w);
        // combine the 4 edge-groups
        s.x += __shfl_xor(s.x, 16); s.x += __shfl_xor(s.x, 32);
        s.y += __shfl_xor(s.y, 16); s.y += __shfl_xor(s.y, 32);
        s.z += __shfl_xor(s.z, 16); s.z += __shfl_xor(s.z, 32);
        s.w += __shfl_xor(s.w, 16); s.w += __shfl_xor(s.w, 32);
        // stage s (features 4*sub..4*sub+3 live at lane sub) into LDS
        if (grp == 0) {
            smw[4 * sub + 0] = s.x; smw[4 * sub + 1] = s.y;
            smw[4 * sub + 2] = s.z; smw[4 * sub + 3] = s.w;
        }
        __builtin_amdgcn_s_waitcnt(WAITCNT_LGKM0);  // wave-internal LDS RAW fence
        // matvec via uniform-address (broadcast) b128 reads
        float a0 = 0.f, a1 = 0.f, a2 = 0.f, a3 = 0.f;
        const float4* smv = (const float4*)smw;
        #pragma unroll
        for (int q = 0; q < 16; ++q) {
            float4 sv = smv[q];
            a0 += sv.x * Wc[4 * q + 0];
            a1 += sv.y * Wc[4 * q + 1];
            a2 += sv.z * Wc[4 * q + 2];
            a3 += sv.w * Wc[4 * q + 3];
        }
        float o = ((a0 + a1) + (a2 + a3)) * rcnt[n] + bl;
        h_out[(size_t)n * L + lane] = __float2half(fmaxf(o, 0.f));
    }
}

// ---------- fused decoder node matvecs: U = h@W1[:64]+b1, V = h@W1[64:] (fp16 out) ----------

__global__ __launch_bounds__(256) void k_mv2(const __half* __restrict__ h,
        const float* __restrict__ W1, const float* __restrict__ b1,
        __half* __restrict__ U, __half* __restrict__ V, int N) {
    __shared__ float sm[4][72];
    int lane = threadIdx.x & 63;
    int warp = threadIdx.x >> 6;
    int wid  = (blockIdx.x * blockDim.x + threadIdx.x) >> 6;
    int nw   = (gridDim.x * blockDim.x) >> 6;
    float* smw = &sm[warp][0];
    float Wu[L], Wv[L];
    #pragma unroll
    for (int f = 0; f < L; ++f) Wu[f] = W1[f * L + lane];
    #pragma unroll
    for (int f = 0; f < L; ++f) Wv[f] = W1[(L + f) * L + lane];
    float bl = b1[lane];
    for (int n = wid; n < N; n += nw) {
        float hl = __half2float(h[(size_t)n * L + lane]);
        smw[lane] = hl;
        __builtin_amdgcn_s_waitcnt(WAITCNT_LGKM0);
        float a0 = 0.f, a1 = 0.f, c0 = 0.f, c1 = 0.f;
        const float4* smv = (const float4*)smw;
        #pragma unroll
        for (int q = 0; q < 16; ++q) {
            float4 sv = smv[q];
            a0 += sv.x * Wu[4 * q + 0] ; a1 += sv.y * Wu[4 * q + 1];
            a0 += sv.z * Wu[4 * q + 2] ; a1 += sv.w * Wu[4 * q + 3];
            c0 += sv.x * Wv[4 * q + 0] ; c1 += sv.y * Wv[4 * q + 1];
            c0 += sv.z * Wv[4 * q + 2] ; c1 += sv.w * Wv[4 * q + 3];
        }
        U[(size_t)n * L + lane] = __float2half((a0 + a1) + bl);
        V[(size_t)n * L + lane] = __float2half(c0 + c1);
        __builtin_amdgcn_s_waitcnt(WAITCNT_LGKM0);  // WAR guard before next store
    }
}

// ---------- decoder edge pass: wave per node, TWO lanes per edge ----------
// writes DENSELY by CSR position into tmp; k_perm permutes to edge order.

__global__ __launch_bounds__(256) void k_edge(const __half* __restrict__ U,
        const __half* __restrict__ V, const float* __restrict__ w2,
        const float* __restrict__ b2,
        const int* __restrict__ colptr, const unsigned* __restrict__ csrX,
        float* __restrict__ tmp, int N) {
    int lane = threadIdx.x & 63;
    int half = lane & 1;               // feature half: [32*half, 32*half+32)
    int wid  = (blockIdx.x * blockDim.x + threadIdx.x) >> 6;
    int nw   = (gridDim.x * blockDim.x) >> 6;
    float w2f[32];
    #pragma unroll
    for (int k = 0; k < 32; ++k) w2f[k] = w2[32 * half + k];
    float b2v = b2[0];

    for (int n = wid; n < N; n += nw) {
        int beg = colptr[n], end = colptr[n + 1];
        const uint4* vrow = (const uint4*)(V + (size_t)n * L + 32 * half);
        uint4 v0 = vrow[0], v1 = vrow[1], v2 = vrow[2], v3 = vrow[3];
        for (int base = beg; base < end; base += 32) {
            int epos = base + (lane >> 1);
            if (epos < end) {
                unsigned md = csrX[epos];
                int r = (int)(md & 0x1FFFFu);
                const uint4* urow = (const uint4*)(U + (size_t)r * L + 32 * half);
                uint4 u0 = urow[0], u1 = urow[1], u2 = urow[2], u3 = urow[3];
                float p = 0.f;
                #define DOT8(uq, vq, B) { \
                    __half2 ta = h2relu(h2add(*(__half2*)&(uq).x, *(__half2*)&(vq).x)); \
                    __half2 tb = h2relu(h2add(*(__half2*)&(uq).y, *(__half2*)&(vq).y)); \
                    __half2 tc = h2relu(h2add(*(__half2*)&(uq).z, *(__half2*)&(vq).z)); \
                    __half2 td = h2relu(h2add(*(__half2*)&(uq).w, *(__half2*)&(vq).w)); \
                    float2 fa = __half22float2(ta), fb = __half22float2(tb); \
                    float2 fc = __half22float2(tc), fd = __half22float2(td); \
                    p += fa.x * w2f[B+0] + fa.y * w2f[B+1] + fb.x * w2f[B+2] + fb.y * w2f[B+3]; \
                    p += fc.x * w2f[B+4] + fc.y * w2f[B+5] + fd.x * w2f[B+6] + fd.y * w2f[B+7]; }
                DOT8(u0, v0, 0) DOT8(u1, v1, 8) DOT8(u2, v2, 16) DOT8(u3, v3, 24)
                #undef DOT8
                p += __shfl_xor(p, 1);     // combine the two halves
                if (half == 0) {
                    float val = p + b2v;
                    if (r == n) val = fmaxf(val, 0.f) + log1pf(expf(-fabsf(val)));
                    tmp[epos] = val;
                }
            }
        }
    }
}

// ---------- permute CSR-ordered results back to edge order (streaming) ----------

__global__ void k_perm(const int* __restrict__ ecol, const int* __restrict__ rank,
                       const int* __restrict__ colptr, const float* __restrict__ tmp,
                       float* __restrict__ out, int E) {
    int e = blockIdx.x * blockDim.x + threadIdx.x;
    if (e < E) out[e] = tmp[colptr[ecol[e]] + rank[e]];
}

// ---------- launch ----------

extern "C" void kernel_launch(void* const* d_in, const int* in_sizes, int n_in,
                              void* d_out, int out_size, void* d_ws, size_t ws_size,
                              hipStream_t stream) {
    const float* x     = (const float*)d_in[0];
    const float* attr  = (const float*)d_in[1];
    const float* w_enc = (const float*)d_in[2];
    const float* b_enc = (const float*)d_in[3];
    const float* c1w   = (const float*)d_in[4];
    const float* c1b   = (const float*)d_in[5];
    const float* c2w   = (const float*)d_in[6];
    const float* c2b   = (const float*)d_in[7];
    const float* dw1   = (const float*)d_in[8];
    const float* db1   = (const float*)d_in[9];
    const float* dw2   = (const float*)d_in[10];
    const float* db2   = (const float*)d_in[11];
    const int*   erow  = (const int*)d_in[12];
    const int*   ecol  = (const int*)d_in[13];
    int N = in_sizes[0];
    int E = in_sizes[1];
    float* out = (float*)d_out;

    char* w = (char*)d_ws;
    auto alloc = [&](size_t bytes) {
        char* p = w; w += (bytes + 255) & ~(size_t)255; return p;
    };
    unsigned long long* degcnt = (unsigned long long*)alloc((size_t)N * 8);  // zeroed
    size_t zbytes = (size_t)(w - (char*)d_ws);
    float* dinv   = (float*)alloc((size_t)N * 4);
    int*   cntI   = (int*)  alloc((size_t)N * 4);
    float* rcnt   = (float*)alloc((size_t)N * 4);
    int*   colptr = (int*)  alloc((size_t)(N + 1) * 4);
    int*   bsums  = (int*)  alloc(((size_t)(N + 1023) / 1024 + 1) * 4);
    int*   rank   = (int*)  alloc((size_t)E * 4);
    unsigned* csrX = (unsigned*)alloc((size_t)E * 4);
    float* tmp    = (float*)alloc((size_t)E * 4);
    __half* hA    = (__half*)alloc((size_t)N * L * 2);   // fp16 h ping
    __half* hB    = (__half*)alloc((size_t)N * L * 2);   // fp16 h pong
    __half* hU    = (__half*)alloc((size_t)N * L * 2);   // decoder U (fp16)
    __half* hV    = (__half*)alloc((size_t)N * L * 2);   // decoder V (fp16)
    (void)ws_size; (void)n_in; (void)out_size;

    (void)hipMemsetAsync(d_ws, 0, zbytes, stream);

    int eb = (E + 255) / 256;
    int nb = (N + 255) / 256;
    int B  = (N + 1023) / 1024;     // scan chunks
    k_hist<<<eb, 256, 0, stream>>>(ecol, attr, degcnt, rank, E);
    k_dinv<<<nb, 256, 0, stream>>>(degcnt, dinv, cntI, rcnt, N);
    k_scan_a<<<B, 256, 0, stream>>>(cntI, bsums, N);
    k_scan_b<<<1, 1024, 0, stream>>>(bsums, B, colptr, N);
    k_scan_c<<<B, 256, 0, stream>>>(cntI, bsums, colptr, N);
    k_scatter<<<eb, 256, 0, stream>>>(erow, ecol, attr, dinv, colptr, rank, csrX, E);
    k_encode<<<(N * L + 255) / 256, 256, 0, stream>>>(x, w_enc, b_enc, hA, N);

    __half* hin = hA; __half* hout = hB;
    for (int i = 0; i < 3; ++i) {
        k_gcn<<<2048, 256, 0, stream>>>((const uint2*)hin, hout, c1w + i * L * L,
                                        c1b + i * L, colptr, csrX, rcnt, N);
        __half* t = hin; hin = hout; hout = t;
        k_gcn<<<2048, 256, 0, stream>>>((const uint2*)hin, hout, c2w + i * L * L,
                                        c2b + i * L, colptr, csrX, rcnt, N);
        t = hin; hin = hout; hout = t;
    }
    // final h in hA (fp16). U -> hU (with b1 folded), V -> hV
    k_mv2<<<2048, 256, 0, stream>>>(hin, dw1, db1, hU, hV, N);
    k_edge<<<2048, 256, 0, stream>>>(hU, hV, dw2, db2, colptr, csrX, tmp, N);
    k_perm<<<eb, 256, 0, stream>>>(ecol, rank, colptr, tmp, out, E);
}